// Round 4
// baseline (2650.634 us; speedup 1.0000x reference)
//
#include <hip/hip_runtime.h>

#define N_NODES 100000
#define E_EDGES 1000000
#define R_REL   3
#define NBATCH  6250          // N_NODES / 16

using bf16x8 = __attribute__((ext_vector_type(8))) short;
using f32x4  = __attribute__((ext_vector_type(4))) float;

__device__ __forceinline__ float lrelu(float x) { return fmaxf(x, 0.2f * x); }

__device__ __forceinline__ short f2bf(float f) {   // RNE f32->bf16
    unsigned u = __builtin_bit_cast(unsigned, f);
    u += 0x7FFFu + ((u >> 16) & 1u);
    return (short)(u >> 16);
}
__device__ __forceinline__ float bf2f(unsigned short u) {
    return __builtin_bit_cast(float, ((unsigned)u) << 16);
}
// swizzled byte offset inside a [16][128] bf16 tile (row stride 256B)
__device__ __forceinline__ int swz(int row, int col) {
    int b = (row << 8) + (col << 1);
    return b ^ ((row & 7) << 4);
}

// ---------------------------------------------------------------------------
// Bake bf16 B-fragments for 16x16x32 MFMA.
// B[k][j]: lane holds j = tj*16 + (lane&15), k = tk*32 + (lane>>4)*8 + e.
// frag element index: ((tj*4+tk)*64 + lane)*8 + e
// ---------------------------------------------------------------------------
__global__ __launch_bounds__(256) void prep_kernel(
    const float* __restrict__ kw, const float* __restrict__ pw,
    const float* __restrict__ lw,
    short* __restrict__ kwB, short* __restrict__ pwB, short* __restrict__ linB)
{
    int idx = blockIdx.x * 256 + threadIdx.x;
    int which, rem;
    if      (idx < 16384) { which = 0; rem = idx; }
    else if (idx < 32768) { which = 1; rem = idx - 16384; }
    else if (idx < 34816) { which = 2; rem = idx - 32768; }
    else return;
    int e = rem & 7, lane = (rem >> 3) & 63, t = rem >> 9;
    int tj = (which == 2) ? 0 : (t >> 2);
    int tk = (which == 2) ? t : (t & 3);
    int j = tj * 16 + (lane & 15);
    int k = tk * 32 + (lane >> 4) * 8 + e;
    const float* src = (which == 0) ? kw : (which == 1) ? pw : lw;
    float v = (which == 2 && j >= 4) ? 0.f : src[j * 128 + k];
    short* dst = (which == 0) ? kwB : (which == 1) ? pwB : linB;
    dst[rem] = f2bf(v);
}

// ---------------------------------------------------------------------------
// h = x @ proj_w.T + pb, via MFMA, stored as bf16. A-frags loaded straight
// from global x (lane -> row=lane&15, k-chunk=(lane>>4)*8). One wave = 16 rows.
// ---------------------------------------------------------------------------
__global__ __launch_bounds__(256) void proj_mfma_kernel(
    const float* __restrict__ x, const short* __restrict__ pwB,
    const float* __restrict__ pb, unsigned short* __restrict__ h_bf)
{
    int wave = threadIdx.x >> 6, lane = threadIdx.x & 63;
    int row16 = lane & 15, kq = lane >> 4;
    for (int b = blockIdx.x * 4 + wave; b < NBATCH; b += gridDim.x * 4) {
        int nbase = b * 16;
        bf16x8 A[4];
        #pragma unroll
        for (int tk = 0; tk < 4; ++tk) {
            const float* px = x + (size_t)(nbase + row16) * 128 + tk * 32 + kq * 8;
            f32x4 lo = *(const f32x4*)px;
            f32x4 hi = *(const f32x4*)(px + 4);
            bf16x8 a;
            a[0] = f2bf(lo[0]); a[1] = f2bf(lo[1]); a[2] = f2bf(lo[2]); a[3] = f2bf(lo[3]);
            a[4] = f2bf(hi[0]); a[5] = f2bf(hi[1]); a[6] = f2bf(hi[2]); a[7] = f2bf(hi[3]);
            A[tk] = a;
        }
        #pragma unroll
        for (int tj = 0; tj < 8; ++tj) {
            f32x4 c = {0.f, 0.f, 0.f, 0.f};
            #pragma unroll
            for (int tk = 0; tk < 4; ++tk) {
                bf16x8 B = *(const bf16x8*)(pwB + ((size_t)(tj * 4 + tk) * 64 + lane) * 8);
                c = __builtin_amdgcn_mfma_f32_16x16x32_bf16(A[tk], B, c, 0, 0, 0);
            }
            int j = tj * 16 + row16;
            float bias = pb[j];
            #pragma unroll
            for (int m = 0; m < 4; ++m) {
                int n = nbase + kq * 4 + m;
                h_bf[(size_t)n * 128 + j] = (unsigned short)f2bf(c[m] + bias);
            }
        }
    }
}

// ---------------------------------------------------------------------------
// a_src/a_dst[r][n][hd] = <h[n,hd,:], att[r,hd,:]>  (thread per (n,hd))
// ---------------------------------------------------------------------------
__global__ __launch_bounds__(256) void a_kernel(
    const unsigned short* __restrict__ h_bf, const float* __restrict__ att_src,
    const float* __restrict__ att_dst,
    float* __restrict__ a_src, float* __restrict__ a_dst)
{
    int idx = blockIdx.x * 256 + threadIdx.x;
    if (idx >= N_NODES * 8) return;
    int n = idx >> 3, hd = idx & 7;
    float hv[16];
    const unsigned short* ph = h_bf + (size_t)n * 128 + hd * 16;
    #pragma unroll
    for (int d = 0; d < 16; ++d) hv[d] = bf2f(ph[d]);
    #pragma unroll
    for (int r = 0; r < 3; ++r) {
        float vs = 0.f, vd = 0.f;
        #pragma unroll
        for (int d = 0; d < 16; ++d) {
            vs += hv[d] * att_src[(r * 8 + hd) * 16 + d];
            vd += hv[d] * att_dst[(r * 8 + hd) * 16 + d];
        }
        a_src[((size_t)r * N_NODES + n) * 8 + hd] = vs;
        a_dst[((size_t)r * N_NODES + n) * 8 + hd] = vd;
    }
}

// --------------------------- CSR build ------------------------------------
__global__ __launch_bounds__(256) void count_kernel(
    const int* __restrict__ e0, const int* __restrict__ e1, const int* __restrict__ e2,
    int* __restrict__ cnt)
{
    int r = blockIdx.y;
    const int* ei = (r == 0) ? e0 : (r == 1) ? e1 : e2;
    int e = blockIdx.x * 256 + threadIdx.x;
    if (e >= E_EDGES) return;
    atomicAdd(&cnt[r * N_NODES + ei[E_EDGES + e]], 1);
}

__global__ __launch_bounds__(256) void scan_kernel(
    const int* __restrict__ cnt, int* __restrict__ off, int* __restrict__ cursor)
{
    int r = blockIdx.x, t = threadIdx.x;
    const int CH = (N_NODES + 255) / 256;
    int lo = t * CH, hi = lo + CH;
    if (hi > N_NODES) hi = N_NODES;
    int s = 0;
    for (int i = lo; i < hi; ++i) s += cnt[r * N_NODES + i];
    __shared__ int part[256];
    part[t] = s;
    __syncthreads();
    for (int d = 1; d < 256; d <<= 1) {
        int v = (t >= d) ? part[t - d] : 0;
        __syncthreads();
        part[t] += v;
        __syncthreads();
    }
    int base = r * E_EDGES + ((t > 0) ? part[t - 1] : 0);
    for (int i = lo; i < hi; ++i) {
        off[r * N_NODES + i] = base;
        cursor[r * N_NODES + i] = base;
        base += cnt[r * N_NODES + i];
    }
}

__global__ __launch_bounds__(256) void fill_kernel(
    const int* __restrict__ e0, const int* __restrict__ e1, const int* __restrict__ e2,
    int* __restrict__ cursor, int* __restrict__ csr_rows)
{
    int r = blockIdx.y;
    const int* ei = (r == 0) ? e0 : (r == 1) ? e1 : e2;
    int e = blockIdx.x * 256 + threadIdx.x;
    if (e >= E_EDGES) return;
    int pos = atomicAdd(&cursor[r * N_NODES + ei[E_EDGES + e]], 1);
    csr_rows[pos] = ei[e];
}

// ------------------- degree counting-sort (perm) ---------------------------
__global__ __launch_bounds__(256) void hist_kernel(const int* __restrict__ cnt,
                                                   int* __restrict__ bins)
{
    int r = blockIdx.y;
    int n = blockIdx.x * 256 + threadIdx.x;
    if (n >= N_NODES) return;
    int d = cnt[r * N_NODES + n]; if (d > 255) d = 255;
    atomicAdd(&bins[r * 256 + d], 1);
}

__global__ __launch_bounds__(256) void binscan_kernel(const int* __restrict__ bins,
                                                      int* __restrict__ bincur)
{
    __shared__ int sh[256];
    int t = threadIdx.x;
    for (int r = 0; r < 3; ++r) {
        sh[t] = bins[r * 256 + t];
        __syncthreads();
        for (int d = 1; d < 256; d <<= 1) {
            int v = (t >= d) ? sh[t - d] : 0;
            __syncthreads();
            sh[t] += v;
            __syncthreads();
        }
        bincur[r * 256 + t] = (t > 0) ? sh[t - 1] : 0;
        __syncthreads();
    }
}

__global__ __launch_bounds__(256) void permfill_kernel(
    const int* __restrict__ cnt, int* __restrict__ bincur, int* __restrict__ perm)
{
    __shared__ int lh[256];
    __shared__ int lbase[256];
    int r = blockIdx.y, t = threadIdx.x;
    int base = blockIdx.x * 1024;
    lh[t] = 0;
    __syncthreads();
    int mybin[4], myloc[4];
    #pragma unroll
    for (int i = 0; i < 4; ++i) {
        int n = base + i * 256 + t;
        int b = 0, loc = 0;
        if (n < N_NODES) {
            b = min(cnt[r * N_NODES + n], 255);
            loc = atomicAdd(&lh[b], 1);
        }
        mybin[i] = b; myloc[i] = loc;
    }
    __syncthreads();
    if (lh[t] > 0) lbase[t] = atomicAdd(&bincur[r * 256 + t], lh[t]);
    __syncthreads();
    #pragma unroll
    for (int i = 0; i < 4; ++i) {
        int n = base + i * 256 + t;
        if (n < N_NODES) perm[r * N_NODES + lbase[mybin[i]] + myloc[i]] = n;
    }
}

// ---------------------------------------------------------------------------
// Fused pull: 8 deg-sorted node-streams per wave (branch-free, prefetched),
// out rows -> LDS bf16 (XOR-swizzled), then MFMA for semantic (8 j-tiles)
// and lin projection (1 tile). No __syncthreads; out_s is wave-private.
// ---------------------------------------------------------------------------
__global__ __launch_bounds__(256) void pull_kernel(
    const unsigned short* __restrict__ h_bf, const float* __restrict__ a_src,
    const float* __restrict__ a_dst, const int* __restrict__ cnt,
    const int* __restrict__ off, const int* __restrict__ csr_rows,
    const int* __restrict__ perm,
    const short* __restrict__ kwB, const short* __restrict__ linB,
    const float* __restrict__ kb,
    float* __restrict__ proj_out, float* __restrict__ red)
{
    __shared__ __align__(16) unsigned short out_s[4][16 * 128];
    int wave = threadIdx.x >> 6, lane = threadIdx.x & 63;
    int r = blockIdx.y;
    int h0 = lane >> 4, h1 = h0 + 4;
    int row16 = lane & 15, kq = lane >> 4;
    const size_t rbase = (size_t)r * N_NODES;
    const int CSR_LAST = R_REL * E_EDGES - 1;
    unsigned short* osw = out_s[wave];

    float kbv[8];
    #pragma unroll
    for (int tj = 0; tj < 8; ++tj) kbv[tj] = kb[tj * 16 + row16];
    float red_acc[8] = {0.f,0.f,0.f,0.f,0.f,0.f,0.f,0.f};

    for (int b = blockIdx.x * 4 + wave; b < NBATCH; b += gridDim.x * 4) {
        #pragma unroll
        for (int half = 0; half < 2; ++half) {
            int deg8[8], st8[8];
            float ad0v[8], ad1v[8];
            int kmax = 0;
            #pragma unroll
            for (int i = 0; i < 8; ++i) {
                int n = perm[r * N_NODES + b * 16 + half * 8 + i];
                size_t rn = rbase + n;
                deg8[i] = cnt[rn];
                st8[i]  = off[rn];
                ad0v[i] = a_dst[rn * 8 + h0];
                ad1v[i] = a_dst[rn * 8 + h1];
                kmax = max(kmax, deg8[i]);
            }
            float a0v[8] = {0,0,0,0,0,0,0,0}, a1v[8] = {0,0,0,0,0,0,0,0};
            float d0v[8] = {0,0,0,0,0,0,0,0}, d1v[8] = {0,0,0,0,0,0,0,0};
            int row8[8];
            #pragma unroll
            for (int i = 0; i < 8; ++i) row8[i] = csr_rows[min(st8[i], CSR_LAST)];

            for (int k = 0; k < kmax; ++k) {
                int nrow[8];
                #pragma unroll
                for (int i = 0; i < 8; ++i) {
                    int dm = deg8[i] - 1; if (dm < 0) dm = 0;
                    int kk = k + 1; if (kk > dm) kk = dm;
                    nrow[i] = csr_rows[min(st8[i] + kk, CSR_LAST)];
                }
                #pragma unroll
                for (int i = 0; i < 8; ++i) {
                    bool live = k < deg8[i];
                    int row = row8[i];
                    size_t rr = rbase + row;
                    float e0 = __expf(lrelu(a_src[rr * 8 + h0] + ad0v[i]));
                    float e1 = __expf(lrelu(a_src[rr * 8 + h1] + ad1v[i]));
                    e0 = live ? e0 : 0.f;
                    e1 = live ? e1 : 0.f;
                    const unsigned short* hr = h_bf + (size_t)row * 128;
                    a0v[i] += e0 * bf2f(hr[lane]);
                    a1v[i] += e1 * bf2f(hr[64 + lane]);
                    d0v[i] += e0;
                    d1v[i] += e1;
                }
                #pragma unroll
                for (int i = 0; i < 8; ++i) row8[i] = nrow[i];
            }
            #pragma unroll
            for (int i = 0; i < 8; ++i) {
                int ri = half * 8 + i;
                float o0 = fmaxf(a0v[i] / (d0v[i] + 1e-16f), 0.f);
                float o1 = fmaxf(a1v[i] / (d1v[i] + 1e-16f), 0.f);
                osw[swz(ri, lane)      >> 1] = (unsigned short)f2bf(o0);
                osw[swz(ri, 64 + lane) >> 1] = (unsigned short)f2bf(o1);
            }
        }

        // A-fragments from swizzled LDS tile
        bf16x8 A[4];
        #pragma unroll
        for (int tk = 0; tk < 4; ++tk) {
            int byte = ((row16 << 8) + (tk << 6) + (kq << 4)) ^ ((row16 & 7) << 4);
            A[tk] = *(const bf16x8*)((const char*)osw + byte);
        }

        // semantic: red[j] += sum_i tanh(out_i . kw_j + kb_j)
        #pragma unroll
        for (int tj = 0; tj < 8; ++tj) {
            f32x4 c = {0.f, 0.f, 0.f, 0.f};
            #pragma unroll
            for (int tk = 0; tk < 4; ++tk) {
                bf16x8 B = *(const bf16x8*)(kwB + ((size_t)(tj * 4 + tk) * 64 + lane) * 8);
                c = __builtin_amdgcn_mfma_f32_16x16x32_bf16(A[tk], B, c, 0, 0, 0);
            }
            float ts = 0.f;
            #pragma unroll
            for (int m = 0; m < 4; ++m) {
                float s = c[m] + kbv[tj];
                float ex = __expf(2.f * s);
                ts += 1.f - 2.f / (ex + 1.f);
            }
            ts += __shfl_xor(ts, 16);
            ts += __shfl_xor(ts, 32);
            red_acc[tj] += ts;
        }

        // lin projection: proj_out[n][0..3] = out_n . lin_w
        {
            f32x4 c = {0.f, 0.f, 0.f, 0.f};
            #pragma unroll
            for (int tk = 0; tk < 4; ++tk) {
                bf16x8 B = *(const bf16x8*)(linB + ((size_t)tk * 64 + lane) * 8);
                c = __builtin_amdgcn_mfma_f32_16x16x32_bf16(A[tk], B, c, 0, 0, 0);
            }
            if (row16 < 4) {
                #pragma unroll
                for (int m = 0; m < 4; ++m) {
                    int n = perm[r * N_NODES + b * 16 + kq * 4 + m];
                    proj_out[(rbase + n) * 4 + row16] = c[m];
                }
            }
        }
    }

    if (lane < 16) {
        #pragma unroll
        for (int tj = 0; tj < 8; ++tj)
            atomicAdd(&red[r * 128 + tj * 16 + lane], red_acc[tj]);
    }
}

// ---------------------------------------------------------------------------
__global__ void attn_kernel(const float* __restrict__ red, const float* __restrict__ q,
                            float* __restrict__ attn)
{
    int lane = threadIdx.x;
    float p[3];
    #pragma unroll
    for (int r = 0; r < 3; ++r) {
        float v = q[lane] * red[r * 128 + lane] + q[lane + 64] * red[r * 128 + lane + 64];
        for (int sft = 32; sft; sft >>= 1) v += __shfl_down(v, sft);
        p[r] = v;
    }
    if (lane == 0) {
        float s0 = p[0] / (float)N_NODES;
        float s1 = p[1] / (float)N_NODES;
        float s2 = p[2] / (float)N_NODES;
        float m = fmaxf(s0, fmaxf(s1, s2));
        float e0 = __expf(s0 - m), e1 = __expf(s1 - m), e2 = __expf(s2 - m);
        float inv = 1.f / (e0 + e1 + e2);
        attn[0] = e0 * inv; attn[1] = e1 * inv; attn[2] = e2 * inv;
    }
}

__global__ __launch_bounds__(256) void final_kernel(
    const float* __restrict__ proj_out, const float* __restrict__ attn,
    const float* __restrict__ lb, float* __restrict__ out)
{
    int i = blockIdx.x * 256 + threadIdx.x;
    if (i >= N_NODES * 4) return;
    int o = i & 3;
    out[i] = attn[0] * proj_out[i]
           + attn[1] * proj_out[(size_t)N_NODES * 4 + i]
           + attn[2] * proj_out[(size_t)2 * N_NODES * 4 + i]
           + lb[o];
}

extern "C" void kernel_launch(void* const* d_in, const int* in_sizes, int n_in,
                              void* d_out, int out_size, void* d_ws, size_t ws_size,
                              hipStream_t stream)
{
    const float* x       = (const float*)d_in[0];
    const int*   e0      = (const int*)d_in[1];
    const int*   e1      = (const int*)d_in[2];
    const int*   e2      = (const int*)d_in[3];
    const float* pw      = (const float*)d_in[4];
    const float* pb      = (const float*)d_in[5];
    const float* att_src = (const float*)d_in[6];
    const float* att_dst = (const float*)d_in[7];
    const float* kw      = (const float*)d_in[8];
    const float* kb      = (const float*)d_in[9];
    const float* q       = (const float*)d_in[10];
    const float* lw      = (const float*)d_in[11];
    const float* lb      = (const float*)d_in[12];
    float* out = (float*)d_out;

    // Workspace layout (float units). Total ~66.5 MB.
    float* ws = (float*)d_ws;
    unsigned short* h_bf = (unsigned short*)ws;        // 12.8M ushort = 6.4M f
    float* a_src    = ws + 6400000;                    // 2,400,000
    float* a_dst    = ws + 8800000;                    // 2,400,000
    float* proj_out = ws + 11200000;                   // 1,200,000
    float* red      = ws + 12400000;                   // 384
    float* attn     = ws + 12400384;                   // 4
    int*   bins     = (int*)(ws + 12400388);           // 768
    int*   bincur   = (int*)(ws + 12401156);           // 768
    short* kwB      = (short*)(ws + 12401924);         // 16384 short
    short* pwB      = (short*)(ws + 12410116);         // 16384 short
    short* linB     = (short*)(ws + 12418308);         // 2048 short
    int*   cnt      = (int*)(ws + 12419332);           // 300,000
    int*   off      = (int*)(ws + 12719332);           // 300,000
    int*   cursor   = (int*)(ws + 13019332);           // 300,000
    int*   csr_rows = (int*)(ws + 13319332);           // 3,000,000
    int*   perm     = (int*)(ws + 16319332);           // 300,000

    hipMemsetAsync(cnt, 0, 300000 * sizeof(int), stream);
    hipMemsetAsync(red, 0, (384 + 4 + 768) * sizeof(float), stream);  // red+attn+bins

    prep_kernel<<<dim3(136), dim3(256), 0, stream>>>(kw, pw, lw, kwB, pwB, linB);
    proj_mfma_kernel<<<dim3(391), dim3(256), 0, stream>>>(x, pwB, pb, h_bf);
    a_kernel<<<dim3(3125), dim3(256), 0, stream>>>(h_bf, att_src, att_dst, a_src, a_dst);
    count_kernel<<<dim3(3907, 3), dim3(256), 0, stream>>>(e0, e1, e2, cnt);
    scan_kernel<<<dim3(3), dim3(256), 0, stream>>>(cnt, off, cursor);
    fill_kernel<<<dim3(3907, 3), dim3(256), 0, stream>>>(e0, e1, e2, cursor, csr_rows);
    hist_kernel<<<dim3(391, 3), dim3(256), 0, stream>>>(cnt, bins);
    binscan_kernel<<<dim3(1), dim3(256), 0, stream>>>(bins, bincur);
    permfill_kernel<<<dim3(98, 3), dim3(256), 0, stream>>>(cnt, bincur, perm);
    pull_kernel<<<dim3(391, 3), dim3(256), 0, stream>>>(h_bf, a_src, a_dst, cnt, off,
                                                        csr_rows, perm, kwB, linB, kb,
                                                        proj_out, red);
    attn_kernel<<<dim3(1), dim3(64), 0, stream>>>(red, q, attn);
    final_kernel<<<dim3(1563), dim3(256), 0, stream>>>(proj_out, attn, lb, out);
}

// Round 5
// 1311.837 us; speedup vs baseline: 2.0206x; 2.0206x over previous
//
#include <hip/hip_runtime.h>

#define N_NODES 100000
#define E_EDGES 1000000
#define R_REL   3
#define NBATCH  6250          // N_NODES / 16

using bf16x8 = __attribute__((ext_vector_type(8))) short;
using f32x4  = __attribute__((ext_vector_type(4))) float;

__device__ __forceinline__ float lrelu(float x) { return fmaxf(x, 0.2f * x); }

__device__ __forceinline__ short f2bf(float f) {   // RNE f32->bf16
    unsigned u = __builtin_bit_cast(unsigned, f);
    u += 0x7FFFu + ((u >> 16) & 1u);
    return (short)(u >> 16);
}
__device__ __forceinline__ float bf2f(unsigned short u) {
    return __builtin_bit_cast(float, ((unsigned)u) << 16);
}

// ---------------------------------------------------------------------------
// Bake bf16 B-fragments for 16x16x32 MFMA (kw, pw full 128x128; lin 4x128).
// B[k][j]: lane holds j = tj*16 + (lane&15), k = tk*32 + (lane>>4)*8 + e.
// ---------------------------------------------------------------------------
__global__ __launch_bounds__(256) void prep_kernel(
    const float* __restrict__ kw, const float* __restrict__ pw,
    const float* __restrict__ lw,
    short* __restrict__ kwB, short* __restrict__ pwB, short* __restrict__ linB)
{
    int idx = blockIdx.x * 256 + threadIdx.x;
    int which, rem;
    if      (idx < 16384) { which = 0; rem = idx; }
    else if (idx < 32768) { which = 1; rem = idx - 16384; }
    else if (idx < 34816) { which = 2; rem = idx - 32768; }
    else return;
    int e = rem & 7, lane = (rem >> 3) & 63, t = rem >> 9;
    int tj = (which == 2) ? 0 : (t >> 2);
    int tk = (which == 2) ? t : (t & 3);
    int j = tj * 16 + (lane & 15);
    int k = tk * 32 + (lane >> 4) * 8 + e;
    const float* src = (which == 0) ? kw : (which == 1) ? pw : lw;
    float v = (which == 2 && j >= 4) ? 0.f : src[j * 128 + k];
    short* dst = (which == 0) ? kwB : (which == 1) ? pwB : linB;
    dst[rem] = f2bf(v);
}

// ---------------------------------------------------------------------------
// h = x @ proj_w.T + pb via MFMA, stored bf16. One wave = 16 rows.
// ---------------------------------------------------------------------------
__global__ __launch_bounds__(256) void proj_mfma_kernel(
    const float* __restrict__ x, const short* __restrict__ pwB,
    const float* __restrict__ pb, unsigned short* __restrict__ h_bf)
{
    int wave = threadIdx.x >> 6, lane = threadIdx.x & 63;
    int row16 = lane & 15, kq = lane >> 4;
    for (int b = blockIdx.x * 4 + wave; b < NBATCH; b += gridDim.x * 4) {
        int nbase = b * 16;
        bf16x8 A[4];
        #pragma unroll
        for (int tk = 0; tk < 4; ++tk) {
            const float* px = x + (size_t)(nbase + row16) * 128 + tk * 32 + kq * 8;
            f32x4 lo = *(const f32x4*)px;
            f32x4 hi = *(const f32x4*)(px + 4);
            bf16x8 a;
            a[0] = f2bf(lo[0]); a[1] = f2bf(lo[1]); a[2] = f2bf(lo[2]); a[3] = f2bf(lo[3]);
            a[4] = f2bf(hi[0]); a[5] = f2bf(hi[1]); a[6] = f2bf(hi[2]); a[7] = f2bf(hi[3]);
            A[tk] = a;
        }
        #pragma unroll
        for (int tj = 0; tj < 8; ++tj) {
            f32x4 c = {0.f, 0.f, 0.f, 0.f};
            #pragma unroll
            for (int tk = 0; tk < 4; ++tk) {
                bf16x8 B = *(const bf16x8*)(pwB + ((size_t)(tj * 4 + tk) * 64 + lane) * 8);
                c = __builtin_amdgcn_mfma_f32_16x16x32_bf16(A[tk], B, c, 0, 0, 0);
            }
            int j = tj * 16 + row16;
            float bias = pb[j];
            #pragma unroll
            for (int m = 0; m < 4; ++m) {
                int n = nbase + kq * 4 + m;
                h_bf[(size_t)n * 128 + j] = (unsigned short)f2bf(c[m] + bias);
            }
        }
    }
}

// ---------------------------------------------------------------------------
// a_src/a_dst[r][n][hd] = <h[n,hd,:], att[r,hd,:]>  (thread per (n,hd))
// ---------------------------------------------------------------------------
__global__ __launch_bounds__(256) void a_kernel(
    const unsigned short* __restrict__ h_bf, const float* __restrict__ att_src,
    const float* __restrict__ att_dst,
    float* __restrict__ a_src, float* __restrict__ a_dst)
{
    int idx = blockIdx.x * 256 + threadIdx.x;
    if (idx >= N_NODES * 8) return;
    int n = idx >> 3, hd = idx & 7;
    float hv[16];
    const unsigned short* ph = h_bf + (size_t)n * 128 + hd * 16;
    #pragma unroll
    for (int d = 0; d < 16; ++d) hv[d] = bf2f(ph[d]);
    #pragma unroll
    for (int r = 0; r < 3; ++r) {
        float vs = 0.f, vd = 0.f;
        #pragma unroll
        for (int d = 0; d < 16; ++d) {
            vs += hv[d] * att_src[(r * 8 + hd) * 16 + d];
            vd += hv[d] * att_dst[(r * 8 + hd) * 16 + d];
        }
        a_src[((size_t)r * N_NODES + n) * 8 + hd] = vs;
        a_dst[((size_t)r * N_NODES + n) * 8 + hd] = vd;
    }
}

// --------------------------- CSR build ------------------------------------
__global__ __launch_bounds__(256) void count_kernel(
    const int* __restrict__ e0, const int* __restrict__ e1, const int* __restrict__ e2,
    int* __restrict__ cnt)
{
    int r = blockIdx.y;
    const int* ei = (r == 0) ? e0 : (r == 1) ? e1 : e2;
    int e = blockIdx.x * 256 + threadIdx.x;
    if (e >= E_EDGES) return;
    atomicAdd(&cnt[r * N_NODES + ei[E_EDGES + e]], 1);
}

__global__ __launch_bounds__(256) void scan_kernel(
    const int* __restrict__ cnt, int* __restrict__ off, int* __restrict__ cursor)
{
    int r = blockIdx.x, t = threadIdx.x;
    const int CH = (N_NODES + 255) / 256;
    int lo = t * CH, hi = lo + CH;
    if (hi > N_NODES) hi = N_NODES;
    int s = 0;
    for (int i = lo; i < hi; ++i) s += cnt[r * N_NODES + i];
    __shared__ int part[256];
    part[t] = s;
    __syncthreads();
    for (int d = 1; d < 256; d <<= 1) {
        int v = (t >= d) ? part[t - d] : 0;
        __syncthreads();
        part[t] += v;
        __syncthreads();
    }
    int base = r * E_EDGES + ((t > 0) ? part[t - 1] : 0);
    for (int i = lo; i < hi; ++i) {
        off[r * N_NODES + i] = base;
        cursor[r * N_NODES + i] = base;
        base += cnt[r * N_NODES + i];
    }
}

__global__ __launch_bounds__(256) void fill_kernel(
    const int* __restrict__ e0, const int* __restrict__ e1, const int* __restrict__ e2,
    int* __restrict__ cursor, int* __restrict__ csr_rows)
{
    int r = blockIdx.y;
    const int* ei = (r == 0) ? e0 : (r == 1) ? e1 : e2;
    int e = blockIdx.x * 256 + threadIdx.x;
    if (e >= E_EDGES) return;
    int pos = atomicAdd(&cursor[r * N_NODES + ei[E_EDGES + e]], 1);
    csr_rows[pos] = ei[e];
}

// ---------------------------------------------------------------------------
// Pure gather pull for ONE relation. 4 node streams per wave, branch-free,
// prefetched. Lane owns dims {2l, 2l+1} (same head hd=l>>3): ONE exp, ONE
// a_src load, ONE u32 h load per edge-stream. Writes outs row bf16-packed.
// No LDS, no MFMA -> low VGPR, high occupancy.
// ---------------------------------------------------------------------------
__global__ __launch_bounds__(256) void pull_kernel(
    const unsigned short* __restrict__ h_bf, const float* __restrict__ a_src,
    const float* __restrict__ a_dst, const int* __restrict__ cnt,
    const int* __restrict__ off, const int* __restrict__ csr_rows,
    unsigned int* __restrict__ outs_bf, int r)
{
    int wave = threadIdx.x >> 6, lane = threadIdx.x & 63;
    int hd = lane >> 3;
    const size_t rbase = (size_t)r * N_NODES;
    const int CSR_LAST = R_REL * E_EDGES - 1;

    int nb = (blockIdx.x * 4 + wave) * 4;
    if (nb >= N_NODES) return;

    int deg4[4], st4[4];
    float adv[4];
    int kmax = 0;
    #pragma unroll
    for (int i = 0; i < 4; ++i) {
        int n = nb + i;
        int nc = (n < N_NODES) ? n : (N_NODES - 1);
        size_t rn = rbase + nc;
        int d = (n < N_NODES) ? cnt[rn] : 0;
        deg4[i] = d;
        st4[i]  = off[rn];
        adv[i]  = a_dst[rn * 8 + hd];
        kmax = max(kmax, d);
    }
    float acc0[4] = {0,0,0,0}, acc1[4] = {0,0,0,0}, den[4] = {0,0,0,0};
    int row4[4];
    #pragma unroll
    for (int i = 0; i < 4; ++i) row4[i] = csr_rows[min(st4[i], CSR_LAST)];

    for (int k = 0; k < kmax; ++k) {
        int nrow[4];
        #pragma unroll
        for (int i = 0; i < 4; ++i) {            // prefetch k+1 (scalar loads)
            int dm = deg4[i] - 1; if (dm < 0) dm = 0;
            int kk = k + 1; if (kk > dm) kk = dm;
            nrow[i] = csr_rows[min(st4[i] + kk, CSR_LAST)];
        }
        #pragma unroll
        for (int i = 0; i < 4; ++i) {
            int row = row4[i];
            float e = __expf(lrelu(a_src[(rbase + row) * 8 + hd] + adv[i]));
            e = (k < deg4[i]) ? e : 0.f;
            unsigned int hv = *(const unsigned int*)(h_bf + (size_t)row * 128 + 2 * lane);
            acc0[i] += e * bf2f((unsigned short)(hv & 0xFFFFu));
            acc1[i] += e * bf2f((unsigned short)(hv >> 16));
            den[i]  += e;
        }
        #pragma unroll
        for (int i = 0; i < 4; ++i) row4[i] = nrow[i];
    }
    #pragma unroll
    for (int i = 0; i < 4; ++i) {
        if (nb + i < N_NODES) {
            float inv = 1.f / (den[i] + 1e-16f);
            float o0 = fmaxf(acc0[i] * inv, 0.f);
            float o1 = fmaxf(acc1[i] * inv, 0.f);
            unsigned int p = (unsigned int)(unsigned short)f2bf(o0)
                           | ((unsigned int)(unsigned short)f2bf(o1) << 16);
            outs_bf[(size_t)(nb + i) * 64 + lane] = p;
        }
    }
}

// ---------------------------------------------------------------------------
// Semantic + lin projection for ONE relation via MFMA. One wave = 16 nodes.
// A-frags straight from global outs_bf; B-frags pre-baked (kwB, linB).
//   red[r][j]      += sum_n tanh(out_n . kw_j + kb_j)
//   proj_out[r][n] = out_n . lin_w   (4 dims)
// ---------------------------------------------------------------------------
__global__ __launch_bounds__(256) void semantic_kernel(
    const unsigned short* __restrict__ outs_bf,
    const short* __restrict__ kwB, const short* __restrict__ linB,
    const float* __restrict__ kb,
    float* __restrict__ proj_out, float* __restrict__ red, int r)
{
    int wave = threadIdx.x >> 6, lane = threadIdx.x & 63;
    int row16 = lane & 15, kq = lane >> 4;
    const size_t rbase = (size_t)r * N_NODES;

    float kbv[8];
    #pragma unroll
    for (int tj = 0; tj < 8; ++tj) kbv[tj] = kb[tj * 16 + row16];
    float red_acc[8] = {0.f,0.f,0.f,0.f,0.f,0.f,0.f,0.f};

    for (int b = blockIdx.x * 4 + wave; b < NBATCH; b += gridDim.x * 4) {
        int nbase = b * 16;
        bf16x8 A[4];
        #pragma unroll
        for (int tk = 0; tk < 4; ++tk)
            A[tk] = *(const bf16x8*)(outs_bf + (size_t)(nbase + row16) * 128 + tk * 32 + kq * 8);

        #pragma unroll
        for (int tj = 0; tj < 8; ++tj) {
            f32x4 c = {0.f, 0.f, 0.f, 0.f};
            #pragma unroll
            for (int tk = 0; tk < 4; ++tk) {
                bf16x8 B = *(const bf16x8*)(kwB + ((size_t)(tj * 4 + tk) * 64 + lane) * 8);
                c = __builtin_amdgcn_mfma_f32_16x16x32_bf16(A[tk], B, c, 0, 0, 0);
            }
            float ts = 0.f;
            #pragma unroll
            for (int m = 0; m < 4; ++m) {
                float s = c[m] + kbv[tj];
                float ex = __expf(2.f * s);
                ts += 1.f - 2.f / (ex + 1.f);
            }
            ts += __shfl_xor(ts, 16);
            ts += __shfl_xor(ts, 32);
            red_acc[tj] += ts;
        }
        {
            f32x4 c = {0.f, 0.f, 0.f, 0.f};
            #pragma unroll
            for (int tk = 0; tk < 4; ++tk) {
                bf16x8 B = *(const bf16x8*)(linB + ((size_t)tk * 64 + lane) * 8);
                c = __builtin_amdgcn_mfma_f32_16x16x32_bf16(A[tk], B, c, 0, 0, 0);
            }
            if (row16 < 4) {
                #pragma unroll
                for (int m = 0; m < 4; ++m) {
                    int n = nbase + kq * 4 + m;
                    proj_out[(rbase + n) * 4 + row16] = c[m];
                }
            }
        }
    }
    if (lane < 16) {
        #pragma unroll
        for (int tj = 0; tj < 8; ++tj)
            atomicAdd(&red[r * 128 + tj * 16 + lane], red_acc[tj]);
    }
}

// ---------------------------------------------------------------------------
__global__ void attn_kernel(const float* __restrict__ red, const float* __restrict__ q,
                            float* __restrict__ attn)
{
    int lane = threadIdx.x;
    float p[3];
    #pragma unroll
    for (int r = 0; r < 3; ++r) {
        float v = q[lane] * red[r * 128 + lane] + q[lane + 64] * red[r * 128 + lane + 64];
        for (int sft = 32; sft; sft >>= 1) v += __shfl_down(v, sft);
        p[r] = v;
    }
    if (lane == 0) {
        float s0 = p[0] / (float)N_NODES;
        float s1 = p[1] / (float)N_NODES;
        float s2 = p[2] / (float)N_NODES;
        float m = fmaxf(s0, fmaxf(s1, s2));
        float e0 = __expf(s0 - m), e1 = __expf(s1 - m), e2 = __expf(s2 - m);
        float inv = 1.f / (e0 + e1 + e2);
        attn[0] = e0 * inv; attn[1] = e1 * inv; attn[2] = e2 * inv;
    }
}

__global__ __launch_bounds__(256) void final_kernel(
    const float* __restrict__ proj_out, const float* __restrict__ attn,
    const float* __restrict__ lb, float* __restrict__ out)
{
    int i = blockIdx.x * 256 + threadIdx.x;
    if (i >= N_NODES * 4) return;
    int o = i & 3;
    out[i] = attn[0] * proj_out[i]
           + attn[1] * proj_out[(size_t)N_NODES * 4 + i]
           + attn[2] * proj_out[(size_t)2 * N_NODES * 4 + i]
           + lb[o];
}

extern "C" void kernel_launch(void* const* d_in, const int* in_sizes, int n_in,
                              void* d_out, int out_size, void* d_ws, size_t ws_size,
                              hipStream_t stream)
{
    const float* x       = (const float*)d_in[0];
    const int*   e0      = (const int*)d_in[1];
    const int*   e1      = (const int*)d_in[2];
    const int*   e2      = (const int*)d_in[3];
    const float* pw      = (const float*)d_in[4];
    const float* pb      = (const float*)d_in[5];
    const float* att_src = (const float*)d_in[6];
    const float* att_dst = (const float*)d_in[7];
    const float* kw      = (const float*)d_in[8];
    const float* kb      = (const float*)d_in[9];
    const float* q       = (const float*)d_in[10];
    const float* lw      = (const float*)d_in[11];
    const float* lb      = (const float*)d_in[12];
    float* out = (float*)d_out;

    // Workspace layout (float units). Total ~91 MB (proven-safe budget).
    float* ws = (float*)d_ws;
    unsigned short* h_bf    = (unsigned short*)ws;     // 12.8M ushort = 6.4M f
    float*          a_src   = ws + 6400000;            // 2,400,000
    float*          a_dst   = ws + 8800000;            // 2,400,000
    unsigned int*   outs_bf = (unsigned int*)(ws + 11200000); // 6.4M u32-equiv (1 relation)
    float*          proj_out= ws + 17600000;           // 1,200,000
    float*          red     = ws + 18800000;           // 384
    float*          attn    = ws + 18800384;           // 4
    short*          kwB     = (short*)(ws + 18800388); // 16384 short
    short*          pwB     = (short*)(ws + 18808580); // 16384 short
    short*          linB    = (short*)(ws + 18816772); // 2048 short
    int*            cnt     = (int*)(ws + 18817796);   // 300,000
    int*            off     = (int*)(ws + 19117796);   // 300,000
    int*            cursor  = (int*)(ws + 19417796);   // 300,000
    int*            csr_rows= (int*)(ws + 19717796);   // 3,000,000

    hipMemsetAsync(cnt, 0, 300000 * sizeof(int), stream);
    hipMemsetAsync(red, 0, 384 * sizeof(float), stream);

    prep_kernel<<<dim3(136), dim3(256), 0, stream>>>(kw, pw, lw, kwB, pwB, linB);
    proj_mfma_kernel<<<dim3(391), dim3(256), 0, stream>>>(x, pwB, pb, h_bf);
    a_kernel<<<dim3(3125), dim3(256), 0, stream>>>(h_bf, att_src, att_dst, a_src, a_dst);
    count_kernel<<<dim3(3907, 3), dim3(256), 0, stream>>>(e0, e1, e2, cnt);
    scan_kernel<<<dim3(3), dim3(256), 0, stream>>>(cnt, off, cursor);
    fill_kernel<<<dim3(3907, 3), dim3(256), 0, stream>>>(e0, e1, e2, cursor, csr_rows);

    for (int r = 0; r < 3; ++r) {
        pull_kernel<<<dim3(6250), dim3(256), 0, stream>>>(
            h_bf, a_src, a_dst, cnt, off, csr_rows, outs_bf, r);
        semantic_kernel<<<dim3(1563), dim3(256), 0, stream>>>(
            (const unsigned short*)outs_bf, kwB, linB, kb, proj_out, red, r);
    }

    attn_kernel<<<dim3(1), dim3(64), 0, stream>>>(red, q, attn);
    final_kernel<<<dim3(1563), dim3(256), 0, stream>>>(proj_out, attn, lb, out);
}

// Round 6
// 1059.397 us; speedup vs baseline: 2.5020x; 1.2383x over previous
//
#include <hip/hip_runtime.h>

#define N_NODES 100000
#define E_EDGES 1000000
#define R_REL   3
#define NBATCH  6250          // N_NODES / 16

using bf16x8 = __attribute__((ext_vector_type(8))) short;
using f32x4  = __attribute__((ext_vector_type(4))) float;

__device__ __forceinline__ float lrelu(float x) { return fmaxf(x, 0.2f * x); }

__device__ __forceinline__ short f2bf(float f) {   // RNE f32->bf16
    unsigned u = __builtin_bit_cast(unsigned, f);
    u += 0x7FFFu + ((u >> 16) & 1u);
    return (short)(u >> 16);
}
__device__ __forceinline__ float bf2f(unsigned short u) {
    return __builtin_bit_cast(float, ((unsigned)u) << 16);
}

// ---------------------------------------------------------------------------
// Bake bf16 B-fragments for 16x16x32 MFMA (kw, pw full 128x128; lin 4x128).
// B[k][j]: lane holds j = tj*16 + (lane&15), k = tk*32 + (lane>>4)*8 + e.
// ---------------------------------------------------------------------------
__global__ __launch_bounds__(256) void prep_kernel(
    const float* __restrict__ kw, const float* __restrict__ pw,
    const float* __restrict__ lw,
    short* __restrict__ kwB, short* __restrict__ pwB, short* __restrict__ linB)
{
    int idx = blockIdx.x * 256 + threadIdx.x;
    int which, rem;
    if      (idx < 16384) { which = 0; rem = idx; }
    else if (idx < 32768) { which = 1; rem = idx - 16384; }
    else if (idx < 34816) { which = 2; rem = idx - 32768; }
    else return;
    int e = rem & 7, lane = (rem >> 3) & 63, t = rem >> 9;
    int tj = (which == 2) ? 0 : (t >> 2);
    int tk = (which == 2) ? t : (t & 3);
    int j = tj * 16 + (lane & 15);
    int k = tk * 32 + (lane >> 4) * 8 + e;
    const float* src = (which == 0) ? kw : (which == 1) ? pw : lw;
    float v = (which == 2 && j >= 4) ? 0.f : src[j * 128 + k];
    short* dst = (which == 0) ? kwB : (which == 1) ? pwB : linB;
    dst[rem] = f2bf(v);
}

// ---------------------------------------------------------------------------
// h = x @ proj_w.T + pb via MFMA, stored bf16. One wave = 16 rows.
// ---------------------------------------------------------------------------
__global__ __launch_bounds__(256) void proj_mfma_kernel(
    const float* __restrict__ x, const short* __restrict__ pwB,
    const float* __restrict__ pb, unsigned short* __restrict__ h_bf)
{
    int wave = threadIdx.x >> 6, lane = threadIdx.x & 63;
    int row16 = lane & 15, kq = lane >> 4;
    for (int b = blockIdx.x * 4 + wave; b < NBATCH; b += gridDim.x * 4) {
        int nbase = b * 16;
        bf16x8 A[4];
        #pragma unroll
        for (int tk = 0; tk < 4; ++tk) {
            const float* px = x + (size_t)(nbase + row16) * 128 + tk * 32 + kq * 8;
            f32x4 lo = *(const f32x4*)px;
            f32x4 hi = *(const f32x4*)(px + 4);
            bf16x8 a;
            a[0] = f2bf(lo[0]); a[1] = f2bf(lo[1]); a[2] = f2bf(lo[2]); a[3] = f2bf(lo[3]);
            a[4] = f2bf(hi[0]); a[5] = f2bf(hi[1]); a[6] = f2bf(hi[2]); a[7] = f2bf(hi[3]);
            A[tk] = a;
        }
        #pragma unroll
        for (int tj = 0; tj < 8; ++tj) {
            f32x4 c = {0.f, 0.f, 0.f, 0.f};
            #pragma unroll
            for (int tk = 0; tk < 4; ++tk) {
                bf16x8 B = *(const bf16x8*)(pwB + ((size_t)(tj * 4 + tk) * 64 + lane) * 8);
                c = __builtin_amdgcn_mfma_f32_16x16x32_bf16(A[tk], B, c, 0, 0, 0);
            }
            int j = tj * 16 + row16;
            float bias = pb[j];
            #pragma unroll
            for (int m = 0; m < 4; ++m) {
                int n = nbase + kq * 4 + m;
                h_bf[(size_t)n * 128 + j] = (unsigned short)f2bf(c[m] + bias);
            }
        }
    }
}

// ---------------------------------------------------------------------------
// a_src/a_dst[r][n][hd] = <h[n,hd,:], att[r,hd,:]>  (thread per (n,hd))
// ---------------------------------------------------------------------------
__global__ __launch_bounds__(256) void a_kernel(
    const unsigned short* __restrict__ h_bf, const float* __restrict__ att_src,
    const float* __restrict__ att_dst,
    float* __restrict__ a_src, float* __restrict__ a_dst)
{
    int idx = blockIdx.x * 256 + threadIdx.x;
    if (idx >= N_NODES * 8) return;
    int n = idx >> 3, hd = idx & 7;
    float hv[16];
    const unsigned short* ph = h_bf + (size_t)n * 128 + hd * 16;
    #pragma unroll
    for (int d = 0; d < 16; ++d) hv[d] = bf2f(ph[d]);
    #pragma unroll
    for (int r = 0; r < 3; ++r) {
        float vs = 0.f, vd = 0.f;
        #pragma unroll
        for (int d = 0; d < 16; ++d) {
            vs += hv[d] * att_src[(r * 8 + hd) * 16 + d];
            vd += hv[d] * att_dst[(r * 8 + hd) * 16 + d];
        }
        a_src[((size_t)r * N_NODES + n) * 8 + hd] = vs;
        a_dst[((size_t)r * N_NODES + n) * 8 + hd] = vd;
    }
}

// --------------------------- CSR build ------------------------------------
// count: degree histogram; the atomic's return value IS the edge's rank
// within its destination list -> stored (coalesced) for the atomic-free fill.
__global__ __launch_bounds__(256) void count_kernel(
    const int* __restrict__ e0, const int* __restrict__ e1, const int* __restrict__ e2,
    int* __restrict__ cnt, int* __restrict__ rank)
{
    int r = blockIdx.y;
    const int* ei = (r == 0) ? e0 : (r == 1) ? e1 : e2;
    int e = blockIdx.x * 256 + threadIdx.x;
    if (e >= E_EDGES) return;
    int k = atomicAdd(&cnt[r * N_NODES + ei[E_EDGES + e]], 1);
    rank[(size_t)r * E_EDGES + e] = k;
}

__global__ __launch_bounds__(256) void scan_kernel(
    const int* __restrict__ cnt, int* __restrict__ off)
{
    int r = blockIdx.x, t = threadIdx.x;
    const int CH = (N_NODES + 255) / 256;
    int lo = t * CH, hi = lo + CH;
    if (hi > N_NODES) hi = N_NODES;
    int s = 0;
    for (int i = lo; i < hi; ++i) s += cnt[r * N_NODES + i];
    __shared__ int part[256];
    part[t] = s;
    __syncthreads();
    for (int d = 1; d < 256; d <<= 1) {
        int v = (t >= d) ? part[t - d] : 0;
        __syncthreads();
        part[t] += v;
        __syncthreads();
    }
    int base = r * E_EDGES + ((t > 0) ? part[t - 1] : 0);
    for (int i = lo; i < hi; ++i) {
        off[r * N_NODES + i] = base;
        base += cnt[r * N_NODES + i];
    }
}

// fill: pos = off[col] + rank[e]  -- NO atomics.
__global__ __launch_bounds__(256) void fill_kernel(
    const int* __restrict__ e0, const int* __restrict__ e1, const int* __restrict__ e2,
    const int* __restrict__ off, const int* __restrict__ rank,
    int* __restrict__ csr_rows)
{
    int r = blockIdx.y;
    const int* ei = (r == 0) ? e0 : (r == 1) ? e1 : e2;
    int e = blockIdx.x * 256 + threadIdx.x;
    if (e >= E_EDGES) return;
    int col = ei[E_EDGES + e];
    int pos = off[r * N_NODES + col] + rank[(size_t)r * E_EDGES + e];
    csr_rows[pos] = ei[e];
}

// ---------------------------------------------------------------------------
// Pure gather pull for ONE relation. 4 node streams per wave, 2 edges per
// stream per iteration (8 concurrent gather pairs). deg/st wave-uniform in
// SGPRs; csr_rows reads are sequential per stream (L1-resident lines).
// Lane owns dims {2l, 2l+1} (same head hd=l>>3): one exp, one a_src load,
// one u32 h load per edge. No LDS, no MFMA.
// ---------------------------------------------------------------------------
__global__ __launch_bounds__(256) void pull_kernel(
    const unsigned short* __restrict__ h_bf, const float* __restrict__ a_src,
    const float* __restrict__ a_dst, const int* __restrict__ cnt,
    const int* __restrict__ off, const int* __restrict__ csr_rows,
    unsigned int* __restrict__ outs_bf, int r)
{
    int wave = threadIdx.x >> 6, lane = threadIdx.x & 63;
    int hd = lane >> 3;
    const size_t rbase = (size_t)r * N_NODES;
    const int CSR_LAST = R_REL * E_EDGES - 1;

    int nb = (blockIdx.x * 4 + wave) * 4;
    if (nb >= N_NODES) return;

    int deg4[4], st4[4];
    float adv[4];
    int kmax = 0;
    #pragma unroll
    for (int i = 0; i < 4; ++i) {
        int n = nb + i;
        int nc = min(n, N_NODES - 1);
        size_t rn = rbase + nc;
        int d = (n < N_NODES) ? cnt[rn] : 0;
        deg4[i] = __builtin_amdgcn_readfirstlane(d);
        st4[i]  = __builtin_amdgcn_readfirstlane(off[rn]);
        adv[i]  = a_dst[rn * 8 + hd];
        kmax = max(kmax, deg4[i]);
    }
    float acc0[4] = {0,0,0,0}, acc1[4] = {0,0,0,0}, den[4] = {0,0,0,0};

    for (int k = 0; k < kmax; k += 2) {
        int rowA[4], rowB[4];
        #pragma unroll
        for (int i = 0; i < 4; ++i) {
            int dm = deg4[i] - 1; if (dm < 0) dm = 0;
            int kA = min(k, dm), kB = min(k + 1, dm);
            rowA[i] = csr_rows[min(st4[i] + kA, CSR_LAST)];
            rowB[i] = csr_rows[min(st4[i] + kB, CSR_LAST)];
        }
        #pragma unroll
        for (int i = 0; i < 4; ++i) {
            float eA = __expf(lrelu(a_src[(rbase + rowA[i]) * 8 + hd] + adv[i]));
            float eB = __expf(lrelu(a_src[(rbase + rowB[i]) * 8 + hd] + adv[i]));
            eA = (k     < deg4[i]) ? eA : 0.f;
            eB = (k + 1 < deg4[i]) ? eB : 0.f;
            unsigned hvA = *(const unsigned*)(h_bf + (size_t)rowA[i] * 128 + 2 * lane);
            unsigned hvB = *(const unsigned*)(h_bf + (size_t)rowB[i] * 128 + 2 * lane);
            acc0[i] += eA * bf2f((unsigned short)(hvA & 0xFFFFu));
            acc1[i] += eA * bf2f((unsigned short)(hvA >> 16));
            den[i]  += eA;
            acc0[i] += eB * bf2f((unsigned short)(hvB & 0xFFFFu));
            acc1[i] += eB * bf2f((unsigned short)(hvB >> 16));
            den[i]  += eB;
        }
    }
    #pragma unroll
    for (int i = 0; i < 4; ++i) {
        if (nb + i < N_NODES) {
            float inv = 1.f / (den[i] + 1e-16f);
            float o0 = fmaxf(acc0[i] * inv, 0.f);
            float o1 = fmaxf(acc1[i] * inv, 0.f);
            unsigned int p = (unsigned int)(unsigned short)f2bf(o0)
                           | ((unsigned int)(unsigned short)f2bf(o1) << 16);
            outs_bf[(size_t)(nb + i) * 64 + lane] = p;
        }
    }
}

// ---------------------------------------------------------------------------
// Semantic + lin projection for ONE relation via MFMA. One wave = 16 nodes.
// ---------------------------------------------------------------------------
__global__ __launch_bounds__(256) void semantic_kernel(
    const unsigned short* __restrict__ outs_bf,
    const short* __restrict__ kwB, const short* __restrict__ linB,
    const float* __restrict__ kb,
    float* __restrict__ proj_out, float* __restrict__ red, int r)
{
    int wave = threadIdx.x >> 6, lane = threadIdx.x & 63;
    int row16 = lane & 15, kq = lane >> 4;
    const size_t rbase = (size_t)r * N_NODES;

    float kbv[8];
    #pragma unroll
    for (int tj = 0; tj < 8; ++tj) kbv[tj] = kb[tj * 16 + row16];
    float red_acc[8] = {0.f,0.f,0.f,0.f,0.f,0.f,0.f,0.f};

    for (int b = blockIdx.x * 4 + wave; b < NBATCH; b += gridDim.x * 4) {
        int nbase = b * 16;
        bf16x8 A[4];
        #pragma unroll
        for (int tk = 0; tk < 4; ++tk)
            A[tk] = *(const bf16x8*)(outs_bf + (size_t)(nbase + row16) * 128 + tk * 32 + kq * 8);

        #pragma unroll
        for (int tj = 0; tj < 8; ++tj) {
            f32x4 c = {0.f, 0.f, 0.f, 0.f};
            #pragma unroll
            for (int tk = 0; tk < 4; ++tk) {
                bf16x8 B = *(const bf16x8*)(kwB + ((size_t)(tj * 4 + tk) * 64 + lane) * 8);
                c = __builtin_amdgcn_mfma_f32_16x16x32_bf16(A[tk], B, c, 0, 0, 0);
            }
            float ts = 0.f;
            #pragma unroll
            for (int m = 0; m < 4; ++m) {
                float s = c[m] + kbv[tj];
                float ex = __expf(2.f * s);
                ts += 1.f - 2.f / (ex + 1.f);
            }
            ts += __shfl_xor(ts, 16);
            ts += __shfl_xor(ts, 32);
            red_acc[tj] += ts;
        }
        {
            f32x4 c = {0.f, 0.f, 0.f, 0.f};
            #pragma unroll
            for (int tk = 0; tk < 4; ++tk) {
                bf16x8 B = *(const bf16x8*)(linB + ((size_t)tk * 64 + lane) * 8);
                c = __builtin_amdgcn_mfma_f32_16x16x32_bf16(A[tk], B, c, 0, 0, 0);
            }
            if (row16 < 4) {
                #pragma unroll
                for (int m = 0; m < 4; ++m) {
                    int n = nbase + kq * 4 + m;
                    proj_out[(rbase + n) * 4 + row16] = c[m];
                }
            }
        }
    }
    if (lane < 16) {
        #pragma unroll
        for (int tj = 0; tj < 8; ++tj)
            atomicAdd(&red[r * 128 + tj * 16 + lane], red_acc[tj]);
    }
}

// ---------------------------------------------------------------------------
__global__ void attn_kernel(const float* __restrict__ red, const float* __restrict__ q,
                            float* __restrict__ attn)
{
    int lane = threadIdx.x;
    float p[3];
    #pragma unroll
    for (int r = 0; r < 3; ++r) {
        float v = q[lane] * red[r * 128 + lane] + q[lane + 64] * red[r * 128 + lane + 64];
        for (int sft = 32; sft; sft >>= 1) v += __shfl_down(v, sft);
        p[r] = v;
    }
    if (lane == 0) {
        float s0 = p[0] / (float)N_NODES;
        float s1 = p[1] / (float)N_NODES;
        float s2 = p[2] / (float)N_NODES;
        float m = fmaxf(s0, fmaxf(s1, s2));
        float e0 = __expf(s0 - m), e1 = __expf(s1 - m), e2 = __expf(s2 - m);
        float inv = 1.f / (e0 + e1 + e2);
        attn[0] = e0 * inv; attn[1] = e1 * inv; attn[2] = e2 * inv;
    }
}

__global__ __launch_bounds__(256) void final_kernel(
    const float* __restrict__ proj_out, const float* __restrict__ attn,
    const float* __restrict__ lb, float* __restrict__ out)
{
    int i = blockIdx.x * 256 + threadIdx.x;
    if (i >= N_NODES * 4) return;
    int o = i & 3;
    out[i] = attn[0] * proj_out[i]
           + attn[1] * proj_out[(size_t)N_NODES * 4 + i]
           + attn[2] * proj_out[(size_t)2 * N_NODES * 4 + i]
           + lb[o];
}

extern "C" void kernel_launch(void* const* d_in, const int* in_sizes, int n_in,
                              void* d_out, int out_size, void* d_ws, size_t ws_size,
                              hipStream_t stream)
{
    const float* x       = (const float*)d_in[0];
    const int*   e0      = (const int*)d_in[1];
    const int*   e1      = (const int*)d_in[2];
    const int*   e2      = (const int*)d_in[3];
    const float* pw      = (const float*)d_in[4];
    const float* pb      = (const float*)d_in[5];
    const float* att_src = (const float*)d_in[6];
    const float* att_dst = (const float*)d_in[7];
    const float* kw      = (const float*)d_in[8];
    const float* kb      = (const float*)d_in[9];
    const float* q       = (const float*)d_in[10];
    const float* lw      = (const float*)d_in[11];
    const float* lb      = (const float*)d_in[12];
    float* out = (float*)d_out;

    // Workspace layout (float units). Total ~91 MB (proven-safe budget).
    // rank (3M ints, 12 MB) ALIASES outs_bf (25.6 MB): rank's lifetime
    // (count->fill) ends before pull writes outs_bf. Same stream => ordered.
    float* ws = (float*)d_ws;
    unsigned short* h_bf    = (unsigned short*)ws;     // 12.8M ushort = 6.4M f
    float*          a_src   = ws + 6400000;            // 2,400,000
    float*          a_dst   = ws + 8800000;            // 2,400,000
    unsigned int*   outs_bf = (unsigned int*)(ws + 11200000); // 6.4M u32 (1 relation)
    int*            rank    = (int*)outs_bf;           // 3M ints, aliased
    float*          proj_out= ws + 17600000;           // 1,200,000
    float*          red     = ws + 18800000;           // 384
    float*          attn    = ws + 18800384;           // 4
    short*          kwB     = (short*)(ws + 18800388); // 16384 short
    short*          pwB     = (short*)(ws + 18808580); // 16384 short
    short*          linB    = (short*)(ws + 18816772); // 2048 short
    int*            cnt     = (int*)(ws + 18817796);   // 300,000
    int*            off     = (int*)(ws + 19117796);   // 300,000
    int*            csr_rows= (int*)(ws + 19417796);   // 3,000,000

    hipMemsetAsync(cnt, 0, 300000 * sizeof(int), stream);
    hipMemsetAsync(red, 0, 384 * sizeof(float), stream);

    prep_kernel<<<dim3(136), dim3(256), 0, stream>>>(kw, pw, lw, kwB, pwB, linB);
    proj_mfma_kernel<<<dim3(391), dim3(256), 0, stream>>>(x, pwB, pb, h_bf);
    a_kernel<<<dim3(3125), dim3(256), 0, stream>>>(h_bf, att_src, att_dst, a_src, a_dst);
    count_kernel<<<dim3(3907, 3), dim3(256), 0, stream>>>(e0, e1, e2, cnt, rank);
    scan_kernel<<<dim3(3), dim3(256), 0, stream>>>(cnt, off);
    fill_kernel<<<dim3(3907, 3), dim3(256), 0, stream>>>(e0, e1, e2, off, rank, csr_rows);

    for (int r = 0; r < 3; ++r) {
        pull_kernel<<<dim3(6250), dim3(256), 0, stream>>>(
            h_bf, a_src, a_dst, cnt, off, csr_rows, outs_bf, r);
        semantic_kernel<<<dim3(1563), dim3(256), 0, stream>>>(
            (const unsigned short*)outs_bf, kwB, linB, kb, proj_out, red, r);
    }

    attn_kernel<<<dim3(1), dim3(64), 0, stream>>>(red, q, attn);
    final_kernel<<<dim3(1563), dim3(256), 0, stream>>>(proj_out, attn, lb, out);
}

// Round 7
// 906.610 us; speedup vs baseline: 2.9237x; 1.1685x over previous
//
#include <hip/hip_runtime.h>

#define N_NODES 100000
#define E_EDGES 1000000
#define R_REL   3
#define NBATCH  6250          // N_NODES / 16
#define NBLK    391           // ceil(N_NODES / 256)

using bf16x8 = __attribute__((ext_vector_type(8))) short;
using f32x4  = __attribute__((ext_vector_type(4))) float;

__device__ __forceinline__ float lrelu(float x) { return fmaxf(x, 0.2f * x); }

__device__ __forceinline__ short f2bf(float f) {   // RNE f32->bf16
    unsigned u = __builtin_bit_cast(unsigned, f);
    u += 0x7FFFu + ((u >> 16) & 1u);
    return (short)(u >> 16);
}
__device__ __forceinline__ float bf2f(unsigned short u) {
    return __builtin_bit_cast(float, ((unsigned)u) << 16);
}

// ---------------------------------------------------------------------------
// Bake bf16 B-fragments for 16x16x32 MFMA (kw, pw full 128x128; lin 4x128).
// B[k][j]: lane holds j = tj*16 + (lane&15), k = tk*32 + (lane>>4)*8 + e.
// ---------------------------------------------------------------------------
__global__ __launch_bounds__(256) void prep_kernel(
    const float* __restrict__ kw, const float* __restrict__ pw,
    const float* __restrict__ lw,
    short* __restrict__ kwB, short* __restrict__ pwB, short* __restrict__ linB)
{
    int idx = blockIdx.x * 256 + threadIdx.x;
    int which, rem;
    if      (idx < 16384) { which = 0; rem = idx; }
    else if (idx < 32768) { which = 1; rem = idx - 16384; }
    else if (idx < 34816) { which = 2; rem = idx - 32768; }
    else return;
    int e = rem & 7, lane = (rem >> 3) & 63, t = rem >> 9;
    int tj = (which == 2) ? 0 : (t >> 2);
    int tk = (which == 2) ? t : (t & 3);
    int j = tj * 16 + (lane & 15);
    int k = tk * 32 + (lane >> 4) * 8 + e;
    const float* src = (which == 0) ? kw : (which == 1) ? pw : lw;
    float v = (which == 2 && j >= 4) ? 0.f : src[j * 128 + k];
    short* dst = (which == 0) ? kwB : (which == 1) ? pwB : linB;
    dst[rem] = f2bf(v);
}

// ---------------------------------------------------------------------------
// h = x @ proj_w.T + pb via MFMA, stored bf16. One wave = 16 rows.
// ---------------------------------------------------------------------------
__global__ __launch_bounds__(256) void proj_mfma_kernel(
    const float* __restrict__ x, const short* __restrict__ pwB,
    const float* __restrict__ pb, unsigned short* __restrict__ h_bf)
{
    int wave = threadIdx.x >> 6, lane = threadIdx.x & 63;
    int row16 = lane & 15, kq = lane >> 4;
    for (int b = blockIdx.x * 4 + wave; b < NBATCH; b += gridDim.x * 4) {
        int nbase = b * 16;
        bf16x8 A[4];
        #pragma unroll
        for (int tk = 0; tk < 4; ++tk) {
            const float* px = x + (size_t)(nbase + row16) * 128 + tk * 32 + kq * 8;
            f32x4 lo = *(const f32x4*)px;
            f32x4 hi = *(const f32x4*)(px + 4);
            bf16x8 a;
            a[0] = f2bf(lo[0]); a[1] = f2bf(lo[1]); a[2] = f2bf(lo[2]); a[3] = f2bf(lo[3]);
            a[4] = f2bf(hi[0]); a[5] = f2bf(hi[1]); a[6] = f2bf(hi[2]); a[7] = f2bf(hi[3]);
            A[tk] = a;
        }
        #pragma unroll
        for (int tj = 0; tj < 8; ++tj) {
            f32x4 c = {0.f, 0.f, 0.f, 0.f};
            #pragma unroll
            for (int tk = 0; tk < 4; ++tk) {
                bf16x8 B = *(const bf16x8*)(pwB + ((size_t)(tj * 4 + tk) * 64 + lane) * 8);
                c = __builtin_amdgcn_mfma_f32_16x16x32_bf16(A[tk], B, c, 0, 0, 0);
            }
            int j = tj * 16 + row16;
            float bias = pb[j];
            #pragma unroll
            for (int m = 0; m < 4; ++m) {
                int n = nbase + kq * 4 + m;
                h_bf[(size_t)n * 128 + j] = (unsigned short)f2bf(c[m] + bias);
            }
        }
    }
}

// ---------------------------------------------------------------------------
// a_src/a_dst[r][n][hd] = <h[n,hd,:], att[r,hd,:]>  (thread per (n,hd))
// ---------------------------------------------------------------------------
__global__ __launch_bounds__(256) void a_kernel(
    const unsigned short* __restrict__ h_bf, const float* __restrict__ att_src,
    const float* __restrict__ att_dst,
    float* __restrict__ a_src, float* __restrict__ a_dst)
{
    int idx = blockIdx.x * 256 + threadIdx.x;
    if (idx >= N_NODES * 8) return;
    int n = idx >> 3, hd = idx & 7;
    float hv[16];
    const unsigned short* ph = h_bf + (size_t)n * 128 + hd * 16;
    #pragma unroll
    for (int d = 0; d < 16; ++d) hv[d] = bf2f(ph[d]);
    #pragma unroll
    for (int r = 0; r < 3; ++r) {
        float vs = 0.f, vd = 0.f;
        #pragma unroll
        for (int d = 0; d < 16; ++d) {
            vs += hv[d] * att_src[(r * 8 + hd) * 16 + d];
            vd += hv[d] * att_dst[(r * 8 + hd) * 16 + d];
        }
        a_src[((size_t)r * N_NODES + n) * 8 + hd] = vs;
        a_dst[((size_t)r * N_NODES + n) * 8 + hd] = vd;
    }
}

// --------------------------- CSR build ------------------------------------
// count: degree histogram; the atomic's return value IS the edge's rank
// within its destination list -> stored (coalesced) for the atomic-free fill.
__global__ __launch_bounds__(256) void count_kernel(
    const int* __restrict__ e0, const int* __restrict__ e1, const int* __restrict__ e2,
    int* __restrict__ cnt, int* __restrict__ rank)
{
    int r = blockIdx.y;
    const int* ei = (r == 0) ? e0 : (r == 1) ? e1 : e2;
    int e = blockIdx.x * 256 + threadIdx.x;
    if (e >= E_EDGES) return;
    int k = atomicAdd(&cnt[r * N_NODES + ei[E_EDGES + e]], 1);
    rank[(size_t)r * E_EDGES + e] = k;
}

// Hierarchical exclusive scan of cnt -> off (3 coalesced, parallel levels).
__global__ __launch_bounds__(256) void bsum_kernel(
    const int* __restrict__ cnt, int* __restrict__ bsums)
{
    __shared__ int sh[256];
    int r = blockIdx.y, b = blockIdx.x, t = threadIdx.x;
    int i = b * 256 + t;
    sh[t] = (i < N_NODES) ? cnt[r * N_NODES + i] : 0;
    __syncthreads();
    for (int d = 128; d > 0; d >>= 1) {
        if (t < d) sh[t] += sh[t + d];
        __syncthreads();
    }
    if (t == 0) bsums[r * NBLK + b] = sh[0];
}

__global__ __launch_bounds__(512) void bscan_kernel(
    const int* __restrict__ bsums, int* __restrict__ bpre)
{
    __shared__ int sh[512];
    int r = blockIdx.x, t = threadIdx.x;
    sh[t] = (t < NBLK) ? bsums[r * NBLK + t] : 0;
    __syncthreads();
    for (int d = 1; d < 512; d <<= 1) {
        int v = (t >= d) ? sh[t - d] : 0;
        __syncthreads();
        sh[t] += v;
        __syncthreads();
    }
    if (t < NBLK) bpre[r * NBLK + t] = (t > 0) ? sh[t - 1] : 0;
}

__global__ __launch_bounds__(256) void offwrite_kernel(
    const int* __restrict__ cnt, const int* __restrict__ bpre,
    int* __restrict__ off)
{
    __shared__ int sh[256];
    int r = blockIdx.y, b = blockIdx.x, t = threadIdx.x;
    int i = b * 256 + t;
    int c = (i < N_NODES) ? cnt[r * N_NODES + i] : 0;
    sh[t] = c;
    __syncthreads();
    for (int d = 1; d < 256; d <<= 1) {
        int v = (t >= d) ? sh[t - d] : 0;
        __syncthreads();
        sh[t] += v;
        __syncthreads();
    }
    if (i < N_NODES)
        off[r * N_NODES + i] = r * E_EDGES + bpre[r * NBLK + b] + (sh[t] - c);
}

// fill: pos = off[col] + rank[e]  -- NO atomics.
__global__ __launch_bounds__(256) void fill_kernel(
    const int* __restrict__ e0, const int* __restrict__ e1, const int* __restrict__ e2,
    const int* __restrict__ off, const int* __restrict__ rank,
    int* __restrict__ csr_rows)
{
    int r = blockIdx.y;
    const int* ei = (r == 0) ? e0 : (r == 1) ? e1 : e2;
    int e = blockIdx.x * 256 + threadIdx.x;
    if (e >= E_EDGES) return;
    int col = ei[E_EDGES + e];
    int pos = off[r * N_NODES + col] + rank[(size_t)r * E_EDGES + e];
    csr_rows[pos] = ei[e];
}

// ---------------------------------------------------------------------------
// Pure gather pull for ONE relation. 4 node streams per wave, 2 edges per
// stream per iteration (8 concurrent gather pairs). deg/st wave-uniform in
// SGPRs; csr_rows reads are sequential per stream (L1-resident lines).
// Lane owns dims {2l, 2l+1} (same head hd=l>>3): one exp, one a_src load,
// one u32 h load per edge. No LDS, no MFMA.
// ---------------------------------------------------------------------------
__global__ __launch_bounds__(256) void pull_kernel(
    const unsigned short* __restrict__ h_bf, const float* __restrict__ a_src,
    const float* __restrict__ a_dst, const int* __restrict__ cnt,
    const int* __restrict__ off, const int* __restrict__ csr_rows,
    unsigned int* __restrict__ outs_bf, int r)
{
    int wave = threadIdx.x >> 6, lane = threadIdx.x & 63;
    int hd = lane >> 3;
    const size_t rbase = (size_t)r * N_NODES;
    const int CSR_LAST = R_REL * E_EDGES - 1;

    int nb = (blockIdx.x * 4 + wave) * 4;
    if (nb >= N_NODES) return;

    int deg4[4], st4[4];
    float adv[4];
    int kmax = 0;
    #pragma unroll
    for (int i = 0; i < 4; ++i) {
        int n = nb + i;
        int nc = min(n, N_NODES - 1);
        size_t rn = rbase + nc;
        int d = (n < N_NODES) ? cnt[rn] : 0;
        deg4[i] = __builtin_amdgcn_readfirstlane(d);
        st4[i]  = __builtin_amdgcn_readfirstlane(off[rn]);
        adv[i]  = a_dst[rn * 8 + hd];
        kmax = max(kmax, deg4[i]);
    }
    float acc0[4] = {0,0,0,0}, acc1[4] = {0,0,0,0}, den[4] = {0,0,0,0};

    for (int k = 0; k < kmax; k += 2) {
        int rowA[4], rowB[4];
        #pragma unroll
        for (int i = 0; i < 4; ++i) {
            int dm = deg4[i] - 1; if (dm < 0) dm = 0;
            int kA = min(k, dm), kB = min(k + 1, dm);
            rowA[i] = csr_rows[min(st4[i] + kA, CSR_LAST)];
            rowB[i] = csr_rows[min(st4[i] + kB, CSR_LAST)];
        }
        #pragma unroll
        for (int i = 0; i < 4; ++i) {
            float eA = __expf(lrelu(a_src[(rbase + rowA[i]) * 8 + hd] + adv[i]));
            float eB = __expf(lrelu(a_src[(rbase + rowB[i]) * 8 + hd] + adv[i]));
            eA = (k     < deg4[i]) ? eA : 0.f;
            eB = (k + 1 < deg4[i]) ? eB : 0.f;
            unsigned hvA = *(const unsigned*)(h_bf + (size_t)rowA[i] * 128 + 2 * lane);
            unsigned hvB = *(const unsigned*)(h_bf + (size_t)rowB[i] * 128 + 2 * lane);
            acc0[i] += eA * bf2f((unsigned short)(hvA & 0xFFFFu));
            acc1[i] += eA * bf2f((unsigned short)(hvA >> 16));
            den[i]  += eA;
            acc0[i] += eB * bf2f((unsigned short)(hvB & 0xFFFFu));
            acc1[i] += eB * bf2f((unsigned short)(hvB >> 16));
            den[i]  += eB;
        }
    }
    #pragma unroll
    for (int i = 0; i < 4; ++i) {
        if (nb + i < N_NODES) {
            float inv = 1.f / (den[i] + 1e-16f);
            float o0 = fmaxf(acc0[i] * inv, 0.f);
            float o1 = fmaxf(acc1[i] * inv, 0.f);
            unsigned int p = (unsigned int)(unsigned short)f2bf(o0)
                           | ((unsigned int)(unsigned short)f2bf(o1) << 16);
            outs_bf[(size_t)(nb + i) * 64 + lane] = p;
        }
    }
}

// ---------------------------------------------------------------------------
// Semantic + lin projection for ONE relation via MFMA. One wave = 16 nodes.
// ---------------------------------------------------------------------------
__global__ __launch_bounds__(256) void semantic_kernel(
    const unsigned short* __restrict__ outs_bf,
    const short* __restrict__ kwB, const short* __restrict__ linB,
    const float* __restrict__ kb,
    float* __restrict__ proj_out, float* __restrict__ red, int r)
{
    int wave = threadIdx.x >> 6, lane = threadIdx.x & 63;
    int row16 = lane & 15, kq = lane >> 4;
    const size_t rbase = (size_t)r * N_NODES;

    float kbv[8];
    #pragma unroll
    for (int tj = 0; tj < 8; ++tj) kbv[tj] = kb[tj * 16 + row16];
    float red_acc[8] = {0.f,0.f,0.f,0.f,0.f,0.f,0.f,0.f};

    for (int b = blockIdx.x * 4 + wave; b < NBATCH; b += gridDim.x * 4) {
        int nbase = b * 16;
        bf16x8 A[4];
        #pragma unroll
        for (int tk = 0; tk < 4; ++tk)
            A[tk] = *(const bf16x8*)(outs_bf + (size_t)(nbase + row16) * 128 + tk * 32 + kq * 8);

        #pragma unroll
        for (int tj = 0; tj < 8; ++tj) {
            f32x4 c = {0.f, 0.f, 0.f, 0.f};
            #pragma unroll
            for (int tk = 0; tk < 4; ++tk) {
                bf16x8 B = *(const bf16x8*)(kwB + ((size_t)(tj * 4 + tk) * 64 + lane) * 8);
                c = __builtin_amdgcn_mfma_f32_16x16x32_bf16(A[tk], B, c, 0, 0, 0);
            }
            float ts = 0.f;
            #pragma unroll
            for (int m = 0; m < 4; ++m) {
                float s = c[m] + kbv[tj];
                float ex = __expf(2.f * s);
                ts += 1.f - 2.f / (ex + 1.f);
            }
            ts += __shfl_xor(ts, 16);
            ts += __shfl_xor(ts, 32);
            red_acc[tj] += ts;
        }
        {
            f32x4 c = {0.f, 0.f, 0.f, 0.f};
            #pragma unroll
            for (int tk = 0; tk < 4; ++tk) {
                bf16x8 B = *(const bf16x8*)(linB + ((size_t)tk * 64 + lane) * 8);
                c = __builtin_amdgcn_mfma_f32_16x16x32_bf16(A[tk], B, c, 0, 0, 0);
            }
            if (row16 < 4) {
                #pragma unroll
                for (int m = 0; m < 4; ++m) {
                    int n = nbase + kq * 4 + m;
                    proj_out[(rbase + n) * 4 + row16] = c[m];
                }
            }
        }
    }
    if (lane < 16) {
        #pragma unroll
        for (int tj = 0; tj < 8; ++tj)
            atomicAdd(&red[r * 128 + tj * 16 + lane], red_acc[tj]);
    }
}

// ---------------------------------------------------------------------------
__global__ void attn_kernel(const float* __restrict__ red, const float* __restrict__ q,
                            float* __restrict__ attn)
{
    int lane = threadIdx.x;
    float p[3];
    #pragma unroll
    for (int r = 0; r < 3; ++r) {
        float v = q[lane] * red[r * 128 + lane] + q[lane + 64] * red[r * 128 + lane + 64];
        for (int sft = 32; sft; sft >>= 1) v += __shfl_down(v, sft);
        p[r] = v;
    }
    if (lane == 0) {
        float s0 = p[0] / (float)N_NODES;
        float s1 = p[1] / (float)N_NODES;
        float s2 = p[2] / (float)N_NODES;
        float m = fmaxf(s0, fmaxf(s1, s2));
        float e0 = __expf(s0 - m), e1 = __expf(s1 - m), e2 = __expf(s2 - m);
        float inv = 1.f / (e0 + e1 + e2);
        attn[0] = e0 * inv; attn[1] = e1 * inv; attn[2] = e2 * inv;
    }
}

__global__ __launch_bounds__(256) void final_kernel(
    const float* __restrict__ proj_out, const float* __restrict__ attn,
    const float* __restrict__ lb, float* __restrict__ out)
{
    int i = blockIdx.x * 256 + threadIdx.x;
    if (i >= N_NODES * 4) return;
    int o = i & 3;
    out[i] = attn[0] * proj_out[i]
           + attn[1] * proj_out[(size_t)N_NODES * 4 + i]
           + attn[2] * proj_out[(size_t)2 * N_NODES * 4 + i]
           + lb[o];
}

extern "C" void kernel_launch(void* const* d_in, const int* in_sizes, int n_in,
                              void* d_out, int out_size, void* d_ws, size_t ws_size,
                              hipStream_t stream)
{
    const float* x       = (const float*)d_in[0];
    const int*   e0      = (const int*)d_in[1];
    const int*   e1      = (const int*)d_in[2];
    const int*   e2      = (const int*)d_in[3];
    const float* pw      = (const float*)d_in[4];
    const float* pb      = (const float*)d_in[5];
    const float* att_src = (const float*)d_in[6];
    const float* att_dst = (const float*)d_in[7];
    const float* kw      = (const float*)d_in[8];
    const float* kb      = (const float*)d_in[9];
    const float* q       = (const float*)d_in[10];
    const float* lw      = (const float*)d_in[11];
    const float* lb      = (const float*)d_in[12];
    float* out = (float*)d_out;

    // Workspace layout (float units). Total ~91 MB (proven-safe budget).
    // rank (3M ints, 12 MB) ALIASES outs_bf (25.6 MB): rank's lifetime
    // (count->fill) ends before pull writes outs_bf. Same stream => ordered.
    float* ws = (float*)d_ws;
    unsigned short* h_bf    = (unsigned short*)ws;     // 12.8M ushort = 6.4M f
    float*          a_src   = ws + 6400000;            // 2,400,000
    float*          a_dst   = ws + 8800000;            // 2,400,000
    unsigned int*   outs_bf = (unsigned int*)(ws + 11200000); // 6.4M u32 (1 relation)
    int*            rank    = (int*)outs_bf;           // 3M ints, aliased
    float*          proj_out= ws + 17600000;           // 1,200,000
    float*          red     = ws + 18800000;           // 384
    float*          attn    = ws + 18800384;           // 4
    short*          kwB     = (short*)(ws + 18800388); // 16384 short
    short*          pwB     = (short*)(ws + 18808580); // 16384 short
    short*          linB    = (short*)(ws + 18816772); // 2048 short
    int*            cnt     = (int*)(ws + 18817796);   // 300,000
    int*            off     = (int*)(ws + 19117796);   // 300,000
    int*            csr_rows= (int*)(ws + 19417796);   // 3,000,000
    int*            bsums   = (int*)(ws + 22417796);   // 1,173
    int*            bpre    = (int*)(ws + 22418969);   // 1,173

    hipMemsetAsync(cnt, 0, 300000 * sizeof(int), stream);
    hipMemsetAsync(red, 0, 384 * sizeof(float), stream);

    prep_kernel<<<dim3(136), dim3(256), 0, stream>>>(kw, pw, lw, kwB, pwB, linB);
    proj_mfma_kernel<<<dim3(391), dim3(256), 0, stream>>>(x, pwB, pb, h_bf);
    a_kernel<<<dim3(3125), dim3(256), 0, stream>>>(h_bf, att_src, att_dst, a_src, a_dst);
    count_kernel<<<dim3(3907, 3), dim3(256), 0, stream>>>(e0, e1, e2, cnt, rank);
    bsum_kernel<<<dim3(NBLK, 3), dim3(256), 0, stream>>>(cnt, bsums);
    bscan_kernel<<<dim3(3), dim3(512), 0, stream>>>(bsums, bpre);
    offwrite_kernel<<<dim3(NBLK, 3), dim3(256), 0, stream>>>(cnt, bpre, off);
    fill_kernel<<<dim3(3907, 3), dim3(256), 0, stream>>>(e0, e1, e2, off, rank, csr_rows);

    for (int r = 0; r < 3; ++r) {
        pull_kernel<<<dim3(6250), dim3(256), 0, stream>>>(
            h_bf, a_src, a_dst, cnt, off, csr_rows, outs_bf, r);
        semantic_kernel<<<dim3(1563), dim3(256), 0, stream>>>(
            (const unsigned short*)outs_bf, kwB, linB, kb, proj_out, red, r);
    }

    attn_kernel<<<dim3(1), dim3(64), 0, stream>>>(red, q, attn);
    final_kernel<<<dim3(1563), dim3(256), 0, stream>>>(proj_out, attn, lb, out);
}

// Round 8
// 580.211 us; speedup vs baseline: 4.5684x; 1.5626x over previous
//
#include <hip/hip_runtime.h>

#define N_NODES 100000
#define E_EDGES 1000000
#define R_REL   3
#define NBATCH  6250          // N_NODES / 16
#define NBLK    391           // ceil(N_NODES / 256)
#define SEMBLK  782           // semantic grid: blocks

using bf16x8 = __attribute__((ext_vector_type(8))) short;
using f32x4  = __attribute__((ext_vector_type(4))) float;

__device__ __forceinline__ float lrelu(float x) { return fmaxf(x, 0.2f * x); }

__device__ __forceinline__ short f2bf(float f) {   // RNE f32->bf16
    unsigned u = __builtin_bit_cast(unsigned, f);
    u += 0x7FFFu + ((u >> 16) & 1u);
    return (short)(u >> 16);
}
__device__ __forceinline__ float bf2f(unsigned short u) {
    return __builtin_bit_cast(float, ((unsigned)u) << 16);
}

// ---------------------------------------------------------------------------
// Bake bf16 B-fragments for 16x16x32 MFMA (kw, pw full 128x128; lin 4x128).
// B[k][j]: lane holds j = tj*16 + (lane&15), k = tk*32 + (lane>>4)*8 + e.
// ---------------------------------------------------------------------------
__global__ __launch_bounds__(256) void prep_kernel(
    const float* __restrict__ kw, const float* __restrict__ pw,
    const float* __restrict__ lw,
    short* __restrict__ kwB, short* __restrict__ pwB, short* __restrict__ linB)
{
    int idx = blockIdx.x * 256 + threadIdx.x;
    int which, rem;
    if      (idx < 16384) { which = 0; rem = idx; }
    else if (idx < 32768) { which = 1; rem = idx - 16384; }
    else if (idx < 34816) { which = 2; rem = idx - 32768; }
    else return;
    int e = rem & 7, lane = (rem >> 3) & 63, t = rem >> 9;
    int tj = (which == 2) ? 0 : (t >> 2);
    int tk = (which == 2) ? t : (t & 3);
    int j = tj * 16 + (lane & 15);
    int k = tk * 32 + (lane >> 4) * 8 + e;
    const float* src = (which == 0) ? kw : (which == 1) ? pw : lw;
    float v = (which == 2 && j >= 4) ? 0.f : src[j * 128 + k];
    short* dst = (which == 0) ? kwB : (which == 1) ? pwB : linB;
    dst[rem] = f2bf(v);
}

// ---------------------------------------------------------------------------
// h = x @ proj_w.T + pb via MFMA, stored bf16. One wave = 16 rows.
// ---------------------------------------------------------------------------
__global__ __launch_bounds__(256) void proj_mfma_kernel(
    const float* __restrict__ x, const short* __restrict__ pwB,
    const float* __restrict__ pb, unsigned short* __restrict__ h_bf)
{
    int wave = threadIdx.x >> 6, lane = threadIdx.x & 63;
    int row16 = lane & 15, kq = lane >> 4;
    for (int b = blockIdx.x * 4 + wave; b < NBATCH; b += gridDim.x * 4) {
        int nbase = b * 16;
        bf16x8 A[4];
        #pragma unroll
        for (int tk = 0; tk < 4; ++tk) {
            const float* px = x + (size_t)(nbase + row16) * 128 + tk * 32 + kq * 8;
            f32x4 lo = *(const f32x4*)px;
            f32x4 hi = *(const f32x4*)(px + 4);
            bf16x8 a;
            a[0] = f2bf(lo[0]); a[1] = f2bf(lo[1]); a[2] = f2bf(lo[2]); a[3] = f2bf(lo[3]);
            a[4] = f2bf(hi[0]); a[5] = f2bf(hi[1]); a[6] = f2bf(hi[2]); a[7] = f2bf(hi[3]);
            A[tk] = a;
        }
        #pragma unroll
        for (int tj = 0; tj < 8; ++tj) {
            f32x4 c = {0.f, 0.f, 0.f, 0.f};
            #pragma unroll
            for (int tk = 0; tk < 4; ++tk) {
                bf16x8 B = *(const bf16x8*)(pwB + ((size_t)(tj * 4 + tk) * 64 + lane) * 8);
                c = __builtin_amdgcn_mfma_f32_16x16x32_bf16(A[tk], B, c, 0, 0, 0);
            }
            int j = tj * 16 + row16;
            float bias = pb[j];
            #pragma unroll
            for (int m = 0; m < 4; ++m) {
                int n = nbase + kq * 4 + m;
                h_bf[(size_t)n * 128 + j] = (unsigned short)f2bf(c[m] + bias);
            }
        }
    }
}

// ---------------------------------------------------------------------------
// a_src/a_dst[r][n][hd] = <h[n,hd,:], att[r,hd,:]>  (thread per (n,hd))
// ---------------------------------------------------------------------------
__global__ __launch_bounds__(256) void a_kernel(
    const unsigned short* __restrict__ h_bf, const float* __restrict__ att_src,
    const float* __restrict__ att_dst,
    float* __restrict__ a_src, float* __restrict__ a_dst)
{
    int idx = blockIdx.x * 256 + threadIdx.x;
    if (idx >= N_NODES * 8) return;
    int n = idx >> 3, hd = idx & 7;
    float hv[16];
    const unsigned short* ph = h_bf + (size_t)n * 128 + hd * 16;
    #pragma unroll
    for (int d = 0; d < 16; ++d) hv[d] = bf2f(ph[d]);
    #pragma unroll
    for (int r = 0; r < 3; ++r) {
        float vs = 0.f, vd = 0.f;
        #pragma unroll
        for (int d = 0; d < 16; ++d) {
            vs += hv[d] * att_src[(r * 8 + hd) * 16 + d];
            vd += hv[d] * att_dst[(r * 8 + hd) * 16 + d];
        }
        a_src[((size_t)r * N_NODES + n) * 8 + hd] = vs;
        a_dst[((size_t)r * N_NODES + n) * 8 + hd] = vd;
    }
}

// --------------------------- CSR build ------------------------------------
__global__ __launch_bounds__(256) void count_kernel(
    const int* __restrict__ e0, const int* __restrict__ e1, const int* __restrict__ e2,
    int* __restrict__ cnt, int* __restrict__ rank)
{
    int r = blockIdx.y;
    const int* ei = (r == 0) ? e0 : (r == 1) ? e1 : e2;
    int e = blockIdx.x * 256 + threadIdx.x;
    if (e >= E_EDGES) return;
    int k = atomicAdd(&cnt[r * N_NODES + ei[E_EDGES + e]], 1);
    rank[(size_t)r * E_EDGES + e] = k;
}

// Hierarchical exclusive scan of cnt -> off (3 coalesced, parallel levels).
__global__ __launch_bounds__(256) void bsum_kernel(
    const int* __restrict__ cnt, int* __restrict__ bsums)
{
    __shared__ int sh[256];
    int r = blockIdx.y, b = blockIdx.x, t = threadIdx.x;
    int i = b * 256 + t;
    sh[t] = (i < N_NODES) ? cnt[r * N_NODES + i] : 0;
    __syncthreads();
    for (int d = 128; d > 0; d >>= 1) {
        if (t < d) sh[t] += sh[t + d];
        __syncthreads();
    }
    if (t == 0) bsums[r * NBLK + b] = sh[0];
}

__global__ __launch_bounds__(512) void bscan_kernel(
    const int* __restrict__ bsums, int* __restrict__ bpre)
{
    __shared__ int sh[512];
    int r = blockIdx.x, t = threadIdx.x;
    sh[t] = (t < NBLK) ? bsums[r * NBLK + t] : 0;
    __syncthreads();
    for (int d = 1; d < 512; d <<= 1) {
        int v = (t >= d) ? sh[t - d] : 0;
        __syncthreads();
        sh[t] += v;
        __syncthreads();
    }
    if (t < NBLK) bpre[r * NBLK + t] = (t > 0) ? sh[t - 1] : 0;
}

__global__ __launch_bounds__(256) void offwrite_kernel(
    const int* __restrict__ cnt, const int* __restrict__ bpre,
    int* __restrict__ off)
{
    __shared__ int sh[256];
    int r = blockIdx.y, b = blockIdx.x, t = threadIdx.x;
    int i = b * 256 + t;
    int c = (i < N_NODES) ? cnt[r * N_NODES + i] : 0;
    sh[t] = c;
    __syncthreads();
    for (int d = 1; d < 256; d <<= 1) {
        int v = (t >= d) ? sh[t - d] : 0;
        __syncthreads();
        sh[t] += v;
        __syncthreads();
    }
    if (i < N_NODES)
        off[r * N_NODES + i] = r * E_EDGES + bpre[r * NBLK + b] + (sh[t] - c);
}

// fill: pos = off[col] + rank[e]  -- NO atomics.
__global__ __launch_bounds__(256) void fill_kernel(
    const int* __restrict__ e0, const int* __restrict__ e1, const int* __restrict__ e2,
    const int* __restrict__ off, const int* __restrict__ rank,
    int* __restrict__ csr_rows)
{
    int r = blockIdx.y;
    const int* ei = (r == 0) ? e0 : (r == 1) ? e1 : e2;
    int e = blockIdx.x * 256 + threadIdx.x;
    if (e >= E_EDGES) return;
    int col = ei[E_EDGES + e];
    int pos = off[r * N_NODES + col] + rank[(size_t)r * E_EDGES + e];
    csr_rows[pos] = ei[e];
}

// ---------------------------------------------------------------------------
// Pure gather pull for ONE relation. 4 node streams per wave, 2 edges per
// stream per iteration (8 concurrent gather pairs). deg/st wave-uniform in
// SGPRs; csr_rows reads sequential per stream. Lane owns dims {2l, 2l+1}.
// ---------------------------------------------------------------------------
__global__ __launch_bounds__(256) void pull_kernel(
    const unsigned short* __restrict__ h_bf, const float* __restrict__ a_src,
    const float* __restrict__ a_dst, const int* __restrict__ cnt,
    const int* __restrict__ off, const int* __restrict__ csr_rows,
    unsigned int* __restrict__ outs_bf, int r)
{
    int wave = threadIdx.x >> 6, lane = threadIdx.x & 63;
    int hd = lane >> 3;
    const size_t rbase = (size_t)r * N_NODES;
    const int CSR_LAST = R_REL * E_EDGES - 1;

    int nb = (blockIdx.x * 4 + wave) * 4;
    if (nb >= N_NODES) return;

    int deg4[4], st4[4];
    float adv[4];
    int kmax = 0;
    #pragma unroll
    for (int i = 0; i < 4; ++i) {
        int n = nb + i;
        int nc = min(n, N_NODES - 1);
        size_t rn = rbase + nc;
        int d = (n < N_NODES) ? cnt[rn] : 0;
        deg4[i] = __builtin_amdgcn_readfirstlane(d);
        st4[i]  = __builtin_amdgcn_readfirstlane(off[rn]);
        adv[i]  = a_dst[rn * 8 + hd];
        kmax = max(kmax, deg4[i]);
    }
    float acc0[4] = {0,0,0,0}, acc1[4] = {0,0,0,0}, den[4] = {0,0,0,0};

    for (int k = 0; k < kmax; k += 2) {
        int rowA[4], rowB[4];
        #pragma unroll
        for (int i = 0; i < 4; ++i) {
            int dm = deg4[i] - 1; if (dm < 0) dm = 0;
            int kA = min(k, dm), kB = min(k + 1, dm);
            rowA[i] = csr_rows[min(st4[i] + kA, CSR_LAST)];
            rowB[i] = csr_rows[min(st4[i] + kB, CSR_LAST)];
        }
        #pragma unroll
        for (int i = 0; i < 4; ++i) {
            float eA = __expf(lrelu(a_src[(rbase + rowA[i]) * 8 + hd] + adv[i]));
            float eB = __expf(lrelu(a_src[(rbase + rowB[i]) * 8 + hd] + adv[i]));
            eA = (k     < deg4[i]) ? eA : 0.f;
            eB = (k + 1 < deg4[i]) ? eB : 0.f;
            unsigned hvA = *(const unsigned*)(h_bf + (size_t)rowA[i] * 128 + 2 * lane);
            unsigned hvB = *(const unsigned*)(h_bf + (size_t)rowB[i] * 128 + 2 * lane);
            acc0[i] += eA * bf2f((unsigned short)(hvA & 0xFFFFu));
            acc1[i] += eA * bf2f((unsigned short)(hvA >> 16));
            den[i]  += eA;
            acc0[i] += eB * bf2f((unsigned short)(hvB & 0xFFFFu));
            acc1[i] += eB * bf2f((unsigned short)(hvB >> 16));
            den[i]  += eB;
        }
    }
    #pragma unroll
    for (int i = 0; i < 4; ++i) {
        if (nb + i < N_NODES) {
            float inv = 1.f / (den[i] + 1e-16f);
            float o0 = fmaxf(acc0[i] * inv, 0.f);
            float o1 = fmaxf(acc1[i] * inv, 0.f);
            unsigned int p = (unsigned int)(unsigned short)f2bf(o0)
                           | ((unsigned int)(unsigned short)f2bf(o1) << 16);
            outs_bf[(size_t)(nb + i) * 64 + lane] = p;
        }
    }
}

// ---------------------------------------------------------------------------
// Semantic + lin projection for ONE relation via MFMA. NO global atomics:
// per-lane red accumulation across batches, one shuffle-reduce at the end,
// 4-wave LDS combine, coalesced per-block partial write to redpart.
// (Round-7 lesson: 6250 waves x 8 atomics on one 512B region = 157us queue.)
// ---------------------------------------------------------------------------
__global__ __launch_bounds__(256) void semantic_kernel(
    const unsigned short* __restrict__ outs_bf,
    const short* __restrict__ kwB, const short* __restrict__ linB,
    const float* __restrict__ kb,
    float* __restrict__ proj_out, float* __restrict__ redpart, int r)
{
    __shared__ float sh[4][128];
    int wave = threadIdx.x >> 6, lane = threadIdx.x & 63;
    int row16 = lane & 15, kq = lane >> 4;
    const size_t rbase = (size_t)r * N_NODES;

    float kbv[8];
    #pragma unroll
    for (int tj = 0; tj < 8; ++tj) kbv[tj] = kb[tj * 16 + row16];
    float red_acc[8] = {0.f,0.f,0.f,0.f,0.f,0.f,0.f,0.f};

    for (int b = blockIdx.x * 4 + wave; b < NBATCH; b += gridDim.x * 4) {
        int nbase = b * 16;
        bf16x8 A[4];
        #pragma unroll
        for (int tk = 0; tk < 4; ++tk)
            A[tk] = *(const bf16x8*)(outs_bf + (size_t)(nbase + row16) * 128 + tk * 32 + kq * 8);

        #pragma unroll
        for (int tj = 0; tj < 8; ++tj) {
            f32x4 c = {0.f, 0.f, 0.f, 0.f};
            #pragma unroll
            for (int tk = 0; tk < 4; ++tk) {
                bf16x8 B = *(const bf16x8*)(kwB + ((size_t)(tj * 4 + tk) * 64 + lane) * 8);
                c = __builtin_amdgcn_mfma_f32_16x16x32_bf16(A[tk], B, c, 0, 0, 0);
            }
            float ts = 0.f;
            #pragma unroll
            for (int m = 0; m < 4; ++m) {
                float s = c[m] + kbv[tj];
                float ex = __expf(2.f * s);
                ts += 1.f - 2.f / (ex + 1.f);
            }
            red_acc[tj] += ts;          // per-lane partial; reduce once at end
        }
        {
            f32x4 c = {0.f, 0.f, 0.f, 0.f};
            #pragma unroll
            for (int tk = 0; tk < 4; ++tk) {
                bf16x8 B = *(const bf16x8*)(linB + ((size_t)tk * 64 + lane) * 8);
                c = __builtin_amdgcn_mfma_f32_16x16x32_bf16(A[tk], B, c, 0, 0, 0);
            }
            if (row16 < 4) {
                #pragma unroll
                for (int m = 0; m < 4; ++m) {
                    int n = nbase + kq * 4 + m;
                    proj_out[(rbase + n) * 4 + row16] = c[m];
                }
            }
        }
    }

    #pragma unroll
    for (int tj = 0; tj < 8; ++tj) {
        float v = red_acc[tj];
        v += __shfl_xor(v, 16);
        v += __shfl_xor(v, 32);
        if (lane < 16) sh[wave][tj * 16 + lane] = v;
    }
    __syncthreads();
    int t = threadIdx.x;
    if (t < 128) {
        float p = sh[0][t] + sh[1][t] + sh[2][t] + sh[3][t];
        redpart[((size_t)r * SEMBLK + blockIdx.x) * 128 + t] = p;
    }
}

// ---------------------------------------------------------------------------
// red[r][j] = sum_b redpart[r][b][j]  (coalesced, L2-resident)
// ---------------------------------------------------------------------------
__global__ __launch_bounds__(256) void redreduce_kernel(
    const float* __restrict__ redpart, float* __restrict__ red)
{
    __shared__ float sh[2][128];
    int r = blockIdx.x;
    int t = threadIdx.x;
    int j = t & 127, half = t >> 7;
    float s = 0.f;
    for (int b = half; b < SEMBLK; b += 2)
        s += redpart[((size_t)r * SEMBLK + b) * 128 + j];
    sh[half][j] = s;
    __syncthreads();
    if (t < 128) red[r * 128 + t] = sh[0][t] + sh[1][t];
}

// ---------------------------------------------------------------------------
__global__ void attn_kernel(const float* __restrict__ red, const float* __restrict__ q,
                            float* __restrict__ attn)
{
    int lane = threadIdx.x;
    float p[3];
    #pragma unroll
    for (int r = 0; r < 3; ++r) {
        float v = q[lane] * red[r * 128 + lane] + q[lane + 64] * red[r * 128 + lane + 64];
        for (int sft = 32; sft; sft >>= 1) v += __shfl_down(v, sft);
        p[r] = v;
    }
    if (lane == 0) {
        float s0 = p[0] / (float)N_NODES;
        float s1 = p[1] / (float)N_NODES;
        float s2 = p[2] / (float)N_NODES;
        float m = fmaxf(s0, fmaxf(s1, s2));
        float e0 = __expf(s0 - m), e1 = __expf(s1 - m), e2 = __expf(s2 - m);
        float inv = 1.f / (e0 + e1 + e2);
        attn[0] = e0 * inv; attn[1] = e1 * inv; attn[2] = e2 * inv;
    }
}

__global__ __launch_bounds__(256) void final_kernel(
    const float* __restrict__ proj_out, const float* __restrict__ attn,
    const float* __restrict__ lb, float* __restrict__ out)
{
    int i = blockIdx.x * 256 + threadIdx.x;
    if (i >= N_NODES * 4) return;
    int o = i & 3;
    out[i] = attn[0] * proj_out[i]
           + attn[1] * proj_out[(size_t)N_NODES * 4 + i]
           + attn[2] * proj_out[(size_t)2 * N_NODES * 4 + i]
           + lb[o];
}

extern "C" void kernel_launch(void* const* d_in, const int* in_sizes, int n_in,
                              void* d_out, int out_size, void* d_ws, size_t ws_size,
                              hipStream_t stream)
{
    const float* x       = (const float*)d_in[0];
    const int*   e0      = (const int*)d_in[1];
    const int*   e1      = (const int*)d_in[2];
    const int*   e2      = (const int*)d_in[3];
    const float* pw      = (const float*)d_in[4];
    const float* pb      = (const float*)d_in[5];
    const float* att_src = (const float*)d_in[6];
    const float* att_dst = (const float*)d_in[7];
    const float* kw      = (const float*)d_in[8];
    const float* kb      = (const float*)d_in[9];
    const float* q       = (const float*)d_in[10];
    const float* lw      = (const float*)d_in[11];
    const float* lb      = (const float*)d_in[12];
    float* out = (float*)d_out;

    // Workspace layout (float units). Total ~90.9 MB (proven-safe budget).
    // rank (3M ints) ALIASES outs_bf: rank dies before pull writes outs_bf.
    float* ws = (float*)d_ws;
    unsigned short* h_bf    = (unsigned short*)ws;     // 12.8M ushort = 6.4M f
    float*          a_src   = ws + 6400000;            // 2,400,000
    float*          a_dst   = ws + 8800000;            // 2,400,000
    unsigned int*   outs_bf = (unsigned int*)(ws + 11200000); // 6.4M u32 (1 relation)
    int*            rank    = (int*)outs_bf;           // 3M ints, aliased
    float*          proj_out= ws + 17600000;           // 1,200,000
    float*          red     = ws + 18800000;           // 384
    float*          attn    = ws + 18800384;           // 4
    short*          kwB     = (short*)(ws + 18800388); // 16384 short
    short*          pwB     = (short*)(ws + 18808580); // 16384 short
    short*          linB    = (short*)(ws + 18816772); // 2048 short
    int*            cnt     = (int*)(ws + 18817796);   // 300,000
    int*            off     = (int*)(ws + 19117796);   // 300,000
    int*            csr_rows= (int*)(ws + 19417796);   // 3,000,000
    int*            bsums   = (int*)(ws + 22417796);   // 1,173
    int*            bpre    = (int*)(ws + 22418969);   // 1,173
    float*          redpart = ws + 22420224;           // 3*782*128 = 300,288

    hipMemsetAsync(cnt, 0, 300000 * sizeof(int), stream);

    prep_kernel<<<dim3(136), dim3(256), 0, stream>>>(kw, pw, lw, kwB, pwB, linB);
    proj_mfma_kernel<<<dim3(391), dim3(256), 0, stream>>>(x, pwB, pb, h_bf);
    a_kernel<<<dim3(3125), dim3(256), 0, stream>>>(h_bf, att_src, att_dst, a_src, a_dst);
    count_kernel<<<dim3(3907, 3), dim3(256), 0, stream>>>(e0, e1, e2, cnt, rank);
    bsum_kernel<<<dim3(NBLK, 3), dim3(256), 0, stream>>>(cnt, bsums);
    bscan_kernel<<<dim3(3), dim3(512), 0, stream>>>(bsums, bpre);
    offwrite_kernel<<<dim3(NBLK, 3), dim3(256), 0, stream>>>(cnt, bpre, off);
    fill_kernel<<<dim3(3907, 3), dim3(256), 0, stream>>>(e0, e1, e2, off, rank, csr_rows);

    for (int r = 0; r < 3; ++r) {
        pull_kernel<<<dim3(6250), dim3(256), 0, stream>>>(
            h_bf, a_src, a_dst, cnt, off, csr_rows, outs_bf, r);
        semantic_kernel<<<dim3(SEMBLK), dim3(256), 0, stream>>>(
            (const unsigned short*)outs_bf, kwB, linB, kb, proj_out, redpart, r);
    }

    redreduce_kernel<<<dim3(3), dim3(256), 0, stream>>>(redpart, red);
    attn_kernel<<<dim3(1), dim3(64), 0, stream>>>(red, q, attn);
    final_kernel<<<dim3(1563), dim3(256), 0, stream>>>(proj_out, attn, lb, out);
}

// Round 9
// 548.789 us; speedup vs baseline: 4.8300x; 1.0573x over previous
//
#include <hip/hip_runtime.h>

#define N_NODES 100000
#define E_EDGES 1000000
#define R_REL   3
#define NBATCH  6250          // N_NODES / 16
#define NBLK    391           // ceil(N_NODES / 256)
#define SEMBLK  782           // semantic grid: blocks

using bf16x8 = __attribute__((ext_vector_type(8))) short;
using f32x4  = __attribute__((ext_vector_type(4))) float;
using u32x2  = __attribute__((ext_vector_type(2))) unsigned int;

__device__ __forceinline__ float lrelu(float x) { return fmaxf(x, 0.2f * x); }

__device__ __forceinline__ short f2bf(float f) {   // RNE f32->bf16
    unsigned u = __builtin_bit_cast(unsigned, f);
    u += 0x7FFFu + ((u >> 16) & 1u);
    return (short)(u >> 16);
}
__device__ __forceinline__ float bf2f(unsigned short u) {
    return __builtin_bit_cast(float, ((unsigned)u) << 16);
}
__device__ __forceinline__ float bf_lo(unsigned u) {   // dims packed lo
    return __builtin_bit_cast(float, u << 16);
}
__device__ __forceinline__ float bf_hi(unsigned u) {
    return __builtin_bit_cast(float, u & 0xFFFF0000u);
}

// ---------------------------------------------------------------------------
// Bake bf16 B-fragments for 16x16x32 MFMA (kw, pw full 128x128; lin 4x128).
// ---------------------------------------------------------------------------
__global__ __launch_bounds__(256) void prep_kernel(
    const float* __restrict__ kw, const float* __restrict__ pw,
    const float* __restrict__ lw,
    short* __restrict__ kwB, short* __restrict__ pwB, short* __restrict__ linB)
{
    int idx = blockIdx.x * 256 + threadIdx.x;
    int which, rem;
    if      (idx < 16384) { which = 0; rem = idx; }
    else if (idx < 32768) { which = 1; rem = idx - 16384; }
    else if (idx < 34816) { which = 2; rem = idx - 32768; }
    else return;
    int e = rem & 7, lane = (rem >> 3) & 63, t = rem >> 9;
    int tj = (which == 2) ? 0 : (t >> 2);
    int tk = (which == 2) ? t : (t & 3);
    int j = tj * 16 + (lane & 15);
    int k = tk * 32 + (lane >> 4) * 8 + e;
    const float* src = (which == 0) ? kw : (which == 1) ? pw : lw;
    float v = (which == 2 && j >= 4) ? 0.f : src[j * 128 + k];
    short* dst = (which == 0) ? kwB : (which == 1) ? pwB : linB;
    dst[rem] = f2bf(v);
}

// ---------------------------------------------------------------------------
// h = x @ proj_w.T + pb via MFMA, stored bf16. One wave = 16 rows.
// ---------------------------------------------------------------------------
__global__ __launch_bounds__(256) void proj_mfma_kernel(
    const float* __restrict__ x, const short* __restrict__ pwB,
    const float* __restrict__ pb, unsigned short* __restrict__ h_bf)
{
    int wave = threadIdx.x >> 6, lane = threadIdx.x & 63;
    int row16 = lane & 15, kq = lane >> 4;
    for (int b = blockIdx.x * 4 + wave; b < NBATCH; b += gridDim.x * 4) {
        int nbase = b * 16;
        bf16x8 A[4];
        #pragma unroll
        for (int tk = 0; tk < 4; ++tk) {
            const float* px = x + (size_t)(nbase + row16) * 128 + tk * 32 + kq * 8;
            f32x4 lo = *(const f32x4*)px;
            f32x4 hi = *(const f32x4*)(px + 4);
            bf16x8 a;
            a[0] = f2bf(lo[0]); a[1] = f2bf(lo[1]); a[2] = f2bf(lo[2]); a[3] = f2bf(lo[3]);
            a[4] = f2bf(hi[0]); a[5] = f2bf(hi[1]); a[6] = f2bf(hi[2]); a[7] = f2bf(hi[3]);
            A[tk] = a;
        }
        #pragma unroll
        for (int tj = 0; tj < 8; ++tj) {
            f32x4 c = {0.f, 0.f, 0.f, 0.f};
            #pragma unroll
            for (int tk = 0; tk < 4; ++tk) {
                bf16x8 B = *(const bf16x8*)(pwB + ((size_t)(tj * 4 + tk) * 64 + lane) * 8);
                c = __builtin_amdgcn_mfma_f32_16x16x32_bf16(A[tk], B, c, 0, 0, 0);
            }
            int j = tj * 16 + row16;
            float bias = pb[j];
            #pragma unroll
            for (int m = 0; m < 4; ++m) {
                int n = nbase + kq * 4 + m;
                h_bf[(size_t)n * 128 + j] = (unsigned short)f2bf(c[m] + bias);
            }
        }
    }
}

// ---------------------------------------------------------------------------
// a_src/a_dst[r][n][hd] = <h[n,hd,:], att[r,hd,:]>  (thread per (n,hd))
// ---------------------------------------------------------------------------
__global__ __launch_bounds__(256) void a_kernel(
    const unsigned short* __restrict__ h_bf, const float* __restrict__ att_src,
    const float* __restrict__ att_dst,
    float* __restrict__ a_src, float* __restrict__ a_dst)
{
    int idx = blockIdx.x * 256 + threadIdx.x;
    if (idx >= N_NODES * 8) return;
    int n = idx >> 3, hd = idx & 7;
    float hv[16];
    const unsigned short* ph = h_bf + (size_t)n * 128 + hd * 16;
    #pragma unroll
    for (int d = 0; d < 16; ++d) hv[d] = bf2f(ph[d]);
    #pragma unroll
    for (int r = 0; r < 3; ++r) {
        float vs = 0.f, vd = 0.f;
        #pragma unroll
        for (int d = 0; d < 16; ++d) {
            vs += hv[d] * att_src[(r * 8 + hd) * 16 + d];
            vd += hv[d] * att_dst[(r * 8 + hd) * 16 + d];
        }
        a_src[((size_t)r * N_NODES + n) * 8 + hd] = vs;
        a_dst[((size_t)r * N_NODES + n) * 8 + hd] = vd;
    }
}

// --------------------------- CSR build ------------------------------------
__global__ __launch_bounds__(256) void count_kernel(
    const int* __restrict__ e0, const int* __restrict__ e1, const int* __restrict__ e2,
    int* __restrict__ cnt, int* __restrict__ rank)
{
    int r = blockIdx.y;
    const int* ei = (r == 0) ? e0 : (r == 1) ? e1 : e2;
    int e = blockIdx.x * 256 + threadIdx.x;
    if (e >= E_EDGES) return;
    int k = atomicAdd(&cnt[r * N_NODES + ei[E_EDGES + e]], 1);
    rank[(size_t)r * E_EDGES + e] = k;
}

// Hierarchical exclusive scan of cnt -> off (3 coalesced, parallel levels).
__global__ __launch_bounds__(256) void bsum_kernel(
    const int* __restrict__ cnt, int* __restrict__ bsums)
{
    __shared__ int sh[256];
    int r = blockIdx.y, b = blockIdx.x, t = threadIdx.x;
    int i = b * 256 + t;
    sh[t] = (i < N_NODES) ? cnt[r * N_NODES + i] : 0;
    __syncthreads();
    for (int d = 128; d > 0; d >>= 1) {
        if (t < d) sh[t] += sh[t + d];
        __syncthreads();
    }
    if (t == 0) bsums[r * NBLK + b] = sh[0];
}

__global__ __launch_bounds__(512) void bscan_kernel(
    const int* __restrict__ bsums, int* __restrict__ bpre)
{
    __shared__ int sh[512];
    int r = blockIdx.x, t = threadIdx.x;
    sh[t] = (t < NBLK) ? bsums[r * NBLK + t] : 0;
    __syncthreads();
    for (int d = 1; d < 512; d <<= 1) {
        int v = (t >= d) ? sh[t - d] : 0;
        __syncthreads();
        sh[t] += v;
        __syncthreads();
    }
    if (t < NBLK) bpre[r * NBLK + t] = (t > 0) ? sh[t - 1] : 0;
}

__global__ __launch_bounds__(256) void offwrite_kernel(
    const int* __restrict__ cnt, const int* __restrict__ bpre,
    int* __restrict__ off)
{
    __shared__ int sh[256];
    int r = blockIdx.y, b = blockIdx.x, t = threadIdx.x;
    int i = b * 256 + t;
    int c = (i < N_NODES) ? cnt[r * N_NODES + i] : 0;
    sh[t] = c;
    __syncthreads();
    for (int d = 1; d < 256; d <<= 1) {
        int v = (t >= d) ? sh[t - d] : 0;
        __syncthreads();
        sh[t] += v;
        __syncthreads();
    }
    if (i < N_NODES)
        off[r * N_NODES + i] = r * E_EDGES + bpre[r * NBLK + b] + (sh[t] - c);
}

// fill: pos = off[col] + rank[e]  -- NO atomics.
__global__ __launch_bounds__(256) void fill_kernel(
    const int* __restrict__ e0, const int* __restrict__ e1, const int* __restrict__ e2,
    const int* __restrict__ off, const int* __restrict__ rank,
    int* __restrict__ csr_rows)
{
    int r = blockIdx.y;
    const int* ei = (r == 0) ? e0 : (r == 1) ? e1 : e2;
    int e = blockIdx.x * 256 + threadIdx.x;
    if (e >= E_EDGES) return;
    int col = ei[E_EDGES + e];
    int pos = off[r * N_NODES + col] + rank[(size_t)r * E_EDGES + e];
    csr_rows[pos] = ei[e];
}

// ---------------------------------------------------------------------------
// HALF-WAVE pull: each 32-lane half owns 4 node streams; lane covers 4 dims
// (one 8B h load). Every wave instruction covers 2 edges -> per-edge VALU
// ~drops 30%, loads/edge 3 -> 2.5. 2-edge unroll per stream keeps 16 gathers
// in flight. deg/st in VGPRs (NOT wave-uniform across halves). Grid exact:
// 3125 blocks x 8 half-units x 4 nodes = 100,000.
// ---------------------------------------------------------------------------
__global__ __launch_bounds__(256) void pull_kernel(
    const unsigned short* __restrict__ h_bf, const float* __restrict__ a_src,
    const float* __restrict__ a_dst, const int* __restrict__ cnt,
    const int* __restrict__ off, const int* __restrict__ csr_rows,
    unsigned int* __restrict__ outs_bf, int r)
{
    int tid = threadIdx.x;
    int wave = tid >> 6, lane = tid & 63;
    int half = lane >> 5, hl = lane & 31;      // half-lane: dims 4hl..4hl+3
    int hd = hl >> 2;                          // head of those dims
    const size_t rbase = (size_t)r * N_NODES;
    const int CSR_LAST = R_REL * E_EDGES - 1;

    int nb = (blockIdx.x * 8 + wave * 2 + half) * 4;   // exact, no tail

    int deg4[4], dm1[4], st4[4];
    float adv[4];
    int kmax = 0;
    #pragma unroll
    for (int i = 0; i < 4; ++i) {
        size_t rn = rbase + (nb + i);
        deg4[i] = cnt[rn];
        st4[i]  = off[rn];
        dm1[i]  = max(deg4[i] - 1, 0);
        adv[i]  = a_dst[rn * 8 + hd];
        kmax = max(kmax, deg4[i]);
    }
    float acc[4][4] = {};
    float den[4] = {0.f, 0.f, 0.f, 0.f};

    for (int k = 0; k < kmax; k += 2) {
        // phase 1: row indices (sequential per stream, L1-resident lines)
        int rowA[4], rowB[4];
        #pragma unroll
        for (int i = 0; i < 4; ++i) {
            int kA = min(k, dm1[i]), kB = min(k + 1, dm1[i]);
            rowA[i] = csr_rows[min(st4[i] + kA, CSR_LAST)];
            rowB[i] = csr_rows[min(st4[i] + kB, CSR_LAST)];
        }
        // phase 2: issue all gathers
        float aA[4], aB[4];
        u32x2 hA[4], hB[4];
        #pragma unroll
        for (int i = 0; i < 4; ++i) {
            aA[i] = a_src[(rbase + rowA[i]) * 8 + hd];
            aB[i] = a_src[(rbase + rowB[i]) * 8 + hd];
            hA[i] = *(const u32x2*)(h_bf + (size_t)rowA[i] * 128 + 4 * hl);
            hB[i] = *(const u32x2*)(h_bf + (size_t)rowB[i] * 128 + 4 * hl);
        }
        // phase 3: compute
        #pragma unroll
        for (int i = 0; i < 4; ++i) {
            float eA = __expf(lrelu(aA[i] + adv[i]));
            float eB = __expf(lrelu(aB[i] + adv[i]));
            eA = (k     < deg4[i]) ? eA : 0.f;
            eB = (k + 1 < deg4[i]) ? eB : 0.f;
            acc[i][0] += eA * bf_lo(hA[i][0]);
            acc[i][1] += eA * bf_hi(hA[i][0]);
            acc[i][2] += eA * bf_lo(hA[i][1]);
            acc[i][3] += eA * bf_hi(hA[i][1]);
            den[i]    += eA;
            acc[i][0] += eB * bf_lo(hB[i][0]);
            acc[i][1] += eB * bf_hi(hB[i][0]);
            acc[i][2] += eB * bf_lo(hB[i][1]);
            acc[i][3] += eB * bf_hi(hB[i][1]);
            den[i]    += eB;
        }
    }
    #pragma unroll
    for (int i = 0; i < 4; ++i) {
        float inv = 1.f / (den[i] + 1e-16f);
        float o0 = fmaxf(acc[i][0] * inv, 0.f);
        float o1 = fmaxf(acc[i][1] * inv, 0.f);
        float o2 = fmaxf(acc[i][2] * inv, 0.f);
        float o3 = fmaxf(acc[i][3] * inv, 0.f);
        u32x2 p;
        p[0] = (unsigned)(unsigned short)f2bf(o0) | ((unsigned)(unsigned short)f2bf(o1) << 16);
        p[1] = (unsigned)(unsigned short)f2bf(o2) | ((unsigned)(unsigned short)f2bf(o3) << 16);
        *(u32x2*)(outs_bf + (size_t)(nb + i) * 64 + 2 * hl) = p;
    }
}

// ---------------------------------------------------------------------------
// Semantic + lin projection for ONE relation via MFMA. NO global atomics.
// ---------------------------------------------------------------------------
__global__ __launch_bounds__(256) void semantic_kernel(
    const unsigned short* __restrict__ outs_bf,
    const short* __restrict__ kwB, const short* __restrict__ linB,
    const float* __restrict__ kb,
    float* __restrict__ proj_out, float* __restrict__ redpart, int r)
{
    __shared__ float sh[4][128];
    int wave = threadIdx.x >> 6, lane = threadIdx.x & 63;
    int row16 = lane & 15, kq = lane >> 4;
    const size_t rbase = (size_t)r * N_NODES;

    float kbv[8];
    #pragma unroll
    for (int tj = 0; tj < 8; ++tj) kbv[tj] = kb[tj * 16 + row16];
    float red_acc[8] = {0.f,0.f,0.f,0.f,0.f,0.f,0.f,0.f};

    for (int b = blockIdx.x * 4 + wave; b < NBATCH; b += gridDim.x * 4) {
        int nbase = b * 16;
        bf16x8 A[4];
        #pragma unroll
        for (int tk = 0; tk < 4; ++tk)
            A[tk] = *(const bf16x8*)(outs_bf + (size_t)(nbase + row16) * 128 + tk * 32 + kq * 8);

        #pragma unroll
        for (int tj = 0; tj < 8; ++tj) {
            f32x4 c = {0.f, 0.f, 0.f, 0.f};
            #pragma unroll
            for (int tk = 0; tk < 4; ++tk) {
                bf16x8 B = *(const bf16x8*)(kwB + ((size_t)(tj * 4 + tk) * 64 + lane) * 8);
                c = __builtin_amdgcn_mfma_f32_16x16x32_bf16(A[tk], B, c, 0, 0, 0);
            }
            float ts = 0.f;
            #pragma unroll
            for (int m = 0; m < 4; ++m) {
                float s = c[m] + kbv[tj];
                float ex = __expf(2.f * s);
                ts += 1.f - 2.f / (ex + 1.f);
            }
            red_acc[tj] += ts;
        }
        {
            f32x4 c = {0.f, 0.f, 0.f, 0.f};
            #pragma unroll
            for (int tk = 0; tk < 4; ++tk) {
                bf16x8 B = *(const bf16x8*)(linB + ((size_t)tk * 64 + lane) * 8);
                c = __builtin_amdgcn_mfma_f32_16x16x32_bf16(A[tk], B, c, 0, 0, 0);
            }
            if (row16 < 4) {
                #pragma unroll
                for (int m = 0; m < 4; ++m) {
                    int n = nbase + kq * 4 + m;
                    proj_out[(rbase + n) * 4 + row16] = c[m];
                }
            }
        }
    }

    #pragma unroll
    for (int tj = 0; tj < 8; ++tj) {
        float v = red_acc[tj];
        v += __shfl_xor(v, 16);
        v += __shfl_xor(v, 32);
        if (lane < 16) sh[wave][tj * 16 + lane] = v;
    }
    __syncthreads();
    int t = threadIdx.x;
    if (t < 128) {
        float p = sh[0][t] + sh[1][t] + sh[2][t] + sh[3][t];
        redpart[((size_t)r * SEMBLK + blockIdx.x) * 128 + t] = p;
    }
}

// ---------------------------------------------------------------------------
__global__ __launch_bounds__(256) void redreduce_kernel(
    const float* __restrict__ redpart, float* __restrict__ red)
{
    __shared__ float sh[2][128];
    int r = blockIdx.x;
    int t = threadIdx.x;
    int j = t & 127, half = t >> 7;
    float s = 0.f;
    for (int b = half; b < SEMBLK; b += 2)
        s += redpart[((size_t)r * SEMBLK + b) * 128 + j];
    sh[half][j] = s;
    __syncthreads();
    if (t < 128) red[r * 128 + t] = sh[0][t] + sh[1][t];
}

// ---------------------------------------------------------------------------
__global__ void attn_kernel(const float* __restrict__ red, const float* __restrict__ q,
                            float* __restrict__ attn)
{
    int lane = threadIdx.x;
    float p[3];
    #pragma unroll
    for (int r = 0; r < 3; ++r) {
        float v = q[lane] * red[r * 128 + lane] + q[lane + 64] * red[r * 128 + lane + 64];
        for (int sft = 32; sft; sft >>= 1) v += __shfl_down(v, sft);
        p[r] = v;
    }
    if (lane == 0) {
        float s0 = p[0] / (float)N_NODES;
        float s1 = p[1] / (float)N_NODES;
        float s2 = p[2] / (float)N_NODES;
        float m = fmaxf(s0, fmaxf(s1, s2));
        float e0 = __expf(s0 - m), e1 = __expf(s1 - m), e2 = __expf(s2 - m);
        float inv = 1.f / (e0 + e1 + e2);
        attn[0] = e0 * inv; attn[1] = e1 * inv; attn[2] = e2 * inv;
    }
}

__global__ __launch_bounds__(256) void final_kernel(
    const float* __restrict__ proj_out, const float* __restrict__ attn,
    const float* __restrict__ lb, float* __restrict__ out)
{
    int i = blockIdx.x * 256 + threadIdx.x;
    if (i >= N_NODES * 4) return;
    int o = i & 3;
    out[i] = attn[0] * proj_out[i]
           + attn[1] * proj_out[(size_t)N_NODES * 4 + i]
           + attn[2] * proj_out[(size_t)2 * N_NODES * 4 + i]
           + lb[o];
}

extern "C" void kernel_launch(void* const* d_in, const int* in_sizes, int n_in,
                              void* d_out, int out_size, void* d_ws, size_t ws_size,
                              hipStream_t stream)
{
    const float* x       = (const float*)d_in[0];
    const int*   e0      = (const int*)d_in[1];
    const int*   e1      = (const int*)d_in[2];
    const int*   e2      = (const int*)d_in[3];
    const float* pw      = (const float*)d_in[4];
    const float* pb      = (const float*)d_in[5];
    const float* att_src = (const float*)d_in[6];
    const float* att_dst = (const float*)d_in[7];
    const float* kw      = (const float*)d_in[8];
    const float* kb      = (const float*)d_in[9];
    const float* q       = (const float*)d_in[10];
    const float* lw      = (const float*)d_in[11];
    const float* lb      = (const float*)d_in[12];
    float* out = (float*)d_out;

    // Workspace layout (float units). Total ~90.9 MB (proven-safe budget).
    // rank (3M ints) ALIASES outs_bf: rank dies before pull writes outs_bf.
    float* ws = (float*)d_ws;
    unsigned short* h_bf    = (unsigned short*)ws;     // 12.8M ushort = 6.4M f
    float*          a_src   = ws + 6400000;            // 2,400,000
    float*          a_dst   = ws + 8800000;            // 2,400,000
    unsigned int*   outs_bf = (unsigned int*)(ws + 11200000); // 6.4M u32 (1 relation)
    int*            rank    = (int*)outs_bf;           // 3M ints, aliased
    float*          proj_out= ws + 17600000;           // 1,200,000
    float*          red     = ws + 18800000;           // 384
    float*          attn    = ws + 18800384;           // 4
    short*          kwB     = (short*)(ws + 18800388); // 16384 short
    short*          pwB     = (short*)(ws + 18808580); // 16384 short
    short*          linB    = (short*)(ws + 18816772); // 2048 short
    int*            cnt     = (int*)(ws + 18817796);   // 300,000
    int*            off     = (int*)(ws + 19117796);   // 300,000
    int*            csr_rows= (int*)(ws + 19417796);   // 3,000,000
    int*            bsums   = (int*)(ws + 22417796);   // 1,173
    int*            bpre    = (int*)(ws + 22418969);   // 1,173
    float*          redpart = ws + 22420224;           // 3*782*128 = 300,288

    hipMemsetAsync(cnt, 0, 300000 * sizeof(int), stream);

    prep_kernel<<<dim3(136), dim3(256), 0, stream>>>(kw, pw, lw, kwB, pwB, linB);
    proj_mfma_kernel<<<dim3(391), dim3(256), 0, stream>>>(x, pwB, pb, h_bf);
    a_kernel<<<dim3(3125), dim3(256), 0, stream>>>(h_bf, att_src, att_dst, a_src, a_dst);
    count_kernel<<<dim3(3907, 3), dim3(256), 0, stream>>>(e0, e1, e2, cnt, rank);
    bsum_kernel<<<dim3(NBLK, 3), dim3(256), 0, stream>>>(cnt, bsums);
    bscan_kernel<<<dim3(3), dim3(512), 0, stream>>>(bsums, bpre);
    offwrite_kernel<<<dim3(NBLK, 3), dim3(256), 0, stream>>>(cnt, bpre, off);
    fill_kernel<<<dim3(3907, 3), dim3(256), 0, stream>>>(e0, e1, e2, off, rank, csr_rows);

    for (int r = 0; r < 3; ++r) {
        pull_kernel<<<dim3(3125), dim3(256), 0, stream>>>(
            h_bf, a_src, a_dst, cnt, off, csr_rows, outs_bf, r);
        semantic_kernel<<<dim3(SEMBLK), dim3(256), 0, stream>>>(
            (const unsigned short*)outs_bf, kwB, linB, kb, proj_out, redpart, r);
    }

    redreduce_kernel<<<dim3(3), dim3(256), 0, stream>>>(redpart, red);
    attn_kernel<<<dim3(1), dim3(64), 0, stream>>>(red, q, attn);
    final_kernel<<<dim3(1563), dim3(256), 0, stream>>>(proj_out, attn, lb, out);
}